// Round 13
// baseline (2115.983 us; speedup 1.0000x reference)
//
#include <hip/hip_runtime.h>
#include <math.h>

// Problem dims
#define B_   256
#define T_   512
#define F_   64
#define H1_  100
#define H2_  128
#define OUT_ 19
#define TCH  128            // timesteps per chunk
#define NCH  (T_/TCH)       // 4 chunks
#define NPC  512            // padded+permuted gate columns (both layers)
#define KP   128            // padded K (units) for both layers

typedef unsigned int uint;
typedef _Float16 h16;
typedef __attribute__((ext_vector_type(2))) _Float16 h16x2;
typedef __attribute__((ext_vector_type(8))) _Float16 f16x8;
typedef __attribute__((ext_vector_type(4))) float f32x4;

// ---- workspace layout (bytes) ----
#define OFF_XP    0ull
#define XP_BYTES  (16ull*TCH*NPC*16*2)     // 33,554,432
#define OFF_H1G   (OFF_XP + XP_BYTES)
#define H1G_BYTES (16ull*TCH*KP*16*2)      // 8,388,608
#define OFF_C1    (OFF_H1G + H1G_BYTES)
#define CST_BYTES (16ull*KP*16*4)          // 131,072
#define OFF_C2    (OFF_C1 + CST_BYTES)
#define OFF_H1S   (OFF_C2 + CST_BYTES)
#define HST_BYTES (16ull*KP*16*2)          // 65,536
#define OFF_H2S   (OFF_H1S + HST_BYTES)
#define WS_NEED   (OFF_H2S + HST_BYTES)    // ~42.3 MB

__device__ __forceinline__ float sigm(float x) { return 1.0f / (1.0f + __expf(-x)); }

__device__ __forceinline__ uint pk2(float a, float b) {
    h16x2 h; h.x = (h16)a; h.y = (h16)b;
    return __builtin_bit_cast(uint, h);
}

__device__ __forceinline__ f32x4 mfma16(f16x8 a, f16x8 b, f32x4 c) {
    return __builtin_amdgcn_mfma_f32_16x16x32_f16(a, b, c, 0, 0, 0);
}

__device__ __forceinline__ f32x4 up4(uint2 v) {
    h16x2 a = __builtin_bit_cast(h16x2, v.x);
    h16x2 b = __builtin_bit_cast(h16x2, v.y);
    f32x4 r; r[0] = (float)a.x; r[1] = (float)a.y; r[2] = (float)b.x; r[3] = (float)b.y;
    return r;
}

// lgkm-only barrier: orders LDS h-writes across waves WITHOUT draining vmcnt,
// so xp prefetch loads / hout stores stay in flight across steps (T4).
__device__ __forceinline__ void bar_lgkm() {
    asm volatile("s_waitcnt lgkmcnt(0)" ::: "memory");
    __builtin_amdgcn_sched_barrier(0);
    __builtin_amdgcn_s_barrier();
    __builtin_amdgcn_sched_barrier(0);
}

// B-fragment loader with gate-column permutation.
// Permuted col c = grp*64 + g*16 + ci  <->  unit u = grp*16+ci, orig col g*H+u.
// Fragment (MFMA 16x16x32 B): lane holds B[k = q*32 + (lane>>4)*8 + e][ci].
__device__ __forceinline__ f16x8 load_bfrag(const float* __restrict__ P, int H, int OG,
                                            int Kreal, int ubase, int g, int q, int lane) {
    const int u  = ubase + (lane & 15);
    const int k0 = q * 32 + (lane >> 4) * 8;
    const int col = g * H + u;
    float f[8];
    #pragma unroll
    for (int e = 0; e < 8; ++e) {
        const int k = k0 + e;
        f[e] = (u < H && k < Kreal) ? P[(size_t)k * OG + col] : 0.0f;
    }
    uint4 r;
    r.x = pk2(f[0], f[1]); r.y = pk2(f[2], f[3]);
    r.z = pk2(f[4], f[5]); r.w = pk2(f[6], f[7]);
    return __builtin_bit_cast(f16x8, r);
}

// ================= dense pre-projection GEMM =================
template<int MODE>
__global__ __launch_bounds__(512) void k_dense(
    const float* __restrict__ Af, const h16* __restrict__ Ah,
    const float* __restrict__ W, const float* __restrict__ bias,
    const int H, const int ch, h16* __restrict__ xp)
{
    const int j = threadIdx.x, lane = j & 63, w = j >> 6;
    const int KF = MODE ? 4 : 2;
    const int KREAL = MODE ? 100 : 64;
    const int OG = 4 * H;

    f16x8 bf[4][4];
    #pragma unroll
    for (int g = 0; g < 4; ++g)
        #pragma unroll
        for (int q = 0; q < 4; ++q)
            if (q < KF) bf[g][q] = load_bfrag(W, H, OG, KREAL, w * 16, g, q, lane);

    float bv[4];
    #pragma unroll
    for (int g = 0; g < 4; ++g) {
        const int u = w * 16 + (lane & 15);
        bv[g] = (u < H) ? bias[g * H + u] : 0.0f;
    }

    const int ci = lane & 15, hi = lane >> 4;
    for (int it = 0; it < 16; ++it) {
        const int m = blockIdx.x * 16 + it;
        const int bt = m >> 7, tc = m & 127;

        f16x8 af[4];
        if (MODE == 0) {
            const int b = bt * 16 + ci;
            const int t = ch * TCH + tc;
            #pragma unroll
            for (int q = 0; q < 2; ++q) {
                const int k0 = q * 32 + hi * 8;
                const float* p = Af + ((size_t)b * T_ + t) * F_ + k0;
                float4 x0 = *(const float4*)p;
                float4 x1 = *(const float4*)(p + 4);
                uint4 r;
                r.x = pk2(x0.x, x0.y); r.y = pk2(x0.z, x0.w);
                r.z = pk2(x1.x, x1.y); r.w = pk2(x1.z, x1.w);
                af[q] = __builtin_bit_cast(f16x8, r);
            }
        } else {
            #pragma unroll
            for (int q = 0; q < 4; ++q) {
                const int k0 = q * 32 + hi * 8;
                const size_t base = ((size_t)(bt * TCH + tc) * KP + k0) * 16 + ci;
                f16x8 a;
                #pragma unroll
                for (int e = 0; e < 8; ++e) a[e] = Ah[base + (size_t)e * 16];
                af[q] = a;
            }
        }

        f32x4 acc[4];
        #pragma unroll
        for (int g = 0; g < 4; ++g) { acc[g][0]=bv[g]; acc[g][1]=bv[g]; acc[g][2]=bv[g]; acc[g][3]=bv[g]; }
        #pragma unroll
        for (int g = 0; g < 4; ++g)
            #pragma unroll
            for (int q = 0; q < 4; ++q)
                if (q < KF) acc[g] = mfma16(af[q], bf[g][q], acc[g]);

        #pragma unroll
        for (int g = 0; g < 4; ++g) {
            const int c = (w * 4 + g) * 16 + ci;
            const size_t o = ((size_t)(bt * TCH + tc) * NPC + c) * 16 + hi * 4;
            uint2 s;
            s.x = pk2(acc[g][0], acc[g][1]);
            s.y = pk2(acc[g][2], acc[g][3]);
            *(uint2*)(xp + o) = s;
        }
    }
}

// ================= recurrence kernel (4 waves / 256 thr) =================
// Each wave owns 2 column-groups (units 32w..32w+31): 32 weight frags = 128 VGPR
// (256-thread grant = 256). A-frags read once, reused by both groups.
#define LFA(G,Q) f16x8 wfA##G##Q = load_bfrag(U, H, 4*H, H, ubA, G, Q, lane); \
                 asm volatile("" ::: "memory");
#define LFB(G,Q) f16x8 wfB##G##Q = load_bfrag(U, H, 4*H, H, ubB, G, Q, lane); \
                 asm volatile("" ::: "memory");

__global__ __launch_bounds__(256, 1) void k_rec(
    const float* __restrict__ U, const int H,
    const h16* __restrict__ xp, h16* __restrict__ hout, const int do_hout,
    float* __restrict__ cstate, h16* __restrict__ hstate, const int ch)
{
    __shared__ h16 hbuf[2][16][136];   // [buf][batch-row][unit], 272B row stride
    const int j = threadIdx.x, lane = j & 63, w = j >> 6;   // w = 0..3
    const int bt = blockIdx.x;
    const int ci = lane & 15, hi = lane >> 4;
    const int ubA = w * 32, ubB = w * 32 + 16;
    const int uA = ubA + ci, uB = ubB + ci;
    const int r0 = hi * 4;

    LFA(0,0) LFA(0,1) LFA(0,2) LFA(0,3)
    LFA(1,0) LFA(1,1) LFA(1,2) LFA(1,3)
    LFA(2,0) LFA(2,1) LFA(2,2) LFA(2,3)
    LFA(3,0) LFA(3,1) LFA(3,2) LFA(3,3)
    LFB(0,0) LFB(0,1) LFB(0,2) LFB(0,3)
    LFB(1,0) LFB(1,1) LFB(1,2) LFB(1,3)
    LFB(2,0) LFB(2,1) LFB(2,2) LFB(2,3)
    LFB(3,0) LFB(3,1) LFB(3,2) LFB(3,3)

    // init hbuf[0] with carried h state (or zeros)
    for (int idx = j; idx < 16 * 128; idx += 256) {
        const int row = idx >> 7, u = idx & 127;
        h16 v = (h16)0.0f;
        if (ch != 0) v = hstate[((size_t)bt * KP + u) * 16 + row];
        hbuf[0][row][u] = v;
    }
    // carried c state (2 units/lane)
    f32x4 cA, cB;
    const size_t coffA = ((size_t)bt * KP + uA) * 16 + r0;
    const size_t coffB = ((size_t)bt * KP + uB) * 16 + r0;
    if (ch == 0) { cA[0]=0.f;cA[1]=0.f;cA[2]=0.f;cA[3]=0.f; cB=cA; }
    else { cA = *(const f32x4*)(cstate + coffA); cB = *(const f32x4*)(cstate + coffB); }
    __syncthreads();

    // xp addressing (h16-element offsets): group A cols w*128+g*16+ci, B +64
    const uint xstep = NPC * 16;
    const uint xbase = (uint)(((size_t)bt * TCH) * NPC) * 16;
    uint xA0 = xbase + (uint)(w * 128 +   0 + ci) * 16 + r0;
    uint xA1 = xA0 + 16 * 16, xA2 = xA0 + 32 * 16, xA3 = xA0 + 48 * 16;
    uint xB0 = xA0 + 64 * 16, xB1 = xB0 + 16 * 16, xB2 = xB0 + 32 * 16, xB3 = xB0 + 48 * 16;
    uint2 nA0 = *(const uint2*)(xp + xA0);
    uint2 nA1 = *(const uint2*)(xp + xA1);
    uint2 nA2 = *(const uint2*)(xp + xA2);
    uint2 nA3 = *(const uint2*)(xp + xA3);
    uint2 nB0 = *(const uint2*)(xp + xB0);
    uint2 nB1 = *(const uint2*)(xp + xB1);
    uint2 nB2 = *(const uint2*)(xp + xB2);
    uint2 nB3 = *(const uint2*)(xp + xB3);

    const uint hstep = KP * 16;
    const uint hobA = (uint)(((size_t)bt * TCH) * KP + uA) * 16 + r0;
    const uint hobB = (uint)(((size_t)bt * TCH) * KP + uB) * 16 + r0;

    uint2 hpA, hpB; hpA.x = hpA.y = hpB.x = hpB.y = 0u;

    for (int t = 0; t < TCH; ++t) {
        const h16* hb = &hbuf[t & 1][0][0];
        f16x8 a0 = *(const f16x8*)(hb + ci * 136 + 0  + hi * 8);
        f16x8 a1 = *(const f16x8*)(hb + ci * 136 + 32 + hi * 8);
        f16x8 a2 = *(const f16x8*)(hb + ci * 136 + 64 + hi * 8);
        f16x8 a3 = *(const f16x8*)(hb + ci * 136 + 96 + hi * 8);

        f32x4 zA0 = up4(nA0), zA1 = up4(nA1), zA2 = up4(nA2), zA3 = up4(nA3);
        f32x4 zB0 = up4(nB0), zB1 = up4(nB1), zB2 = up4(nB2), zB3 = up4(nB3);

        // prefetch next step's xp (stays in flight across the lgkm barrier)
        const uint to = (uint)((t + 1 < TCH) ? t + 1 : t) * xstep;
        nA0 = *(const uint2*)(xp + xA0 + to);
        nA1 = *(const uint2*)(xp + xA1 + to);
        nA2 = *(const uint2*)(xp + xA2 + to);
        nA3 = *(const uint2*)(xp + xA3 + to);
        nB0 = *(const uint2*)(xp + xB0 + to);
        nB1 = *(const uint2*)(xp + xB1 + to);
        nB2 = *(const uint2*)(xp + xB2 + to);
        nB3 = *(const uint2*)(xp + xB3 + to);

        zA0 = mfma16(a0, wfA00, zA0); zA0 = mfma16(a1, wfA01, zA0); zA0 = mfma16(a2, wfA02, zA0); zA0 = mfma16(a3, wfA03, zA0);
        zA1 = mfma16(a0, wfA10, zA1); zA1 = mfma16(a1, wfA11, zA1); zA1 = mfma16(a2, wfA12, zA1); zA1 = mfma16(a3, wfA13, zA1);
        zA2 = mfma16(a0, wfA20, zA2); zA2 = mfma16(a1, wfA21, zA2); zA2 = mfma16(a2, wfA22, zA2); zA2 = mfma16(a3, wfA23, zA2);
        zA3 = mfma16(a0, wfA30, zA3); zA3 = mfma16(a1, wfA31, zA3); zA3 = mfma16(a2, wfA32, zA3); zA3 = mfma16(a3, wfA33, zA3);
        zB0 = mfma16(a0, wfB00, zB0); zB0 = mfma16(a1, wfB01, zB0); zB0 = mfma16(a2, wfB02, zB0); zB0 = mfma16(a3, wfB03, zB0);
        zB1 = mfma16(a0, wfB10, zB1); zB1 = mfma16(a1, wfB11, zB1); zB1 = mfma16(a2, wfB12, zB1); zB1 = mfma16(a3, wfB13, zB1);
        zB2 = mfma16(a0, wfB20, zB2); zB2 = mfma16(a1, wfB21, zB2); zB2 = mfma16(a2, wfB22, zB2); zB2 = mfma16(a3, wfB23, zB2);
        zB3 = mfma16(a0, wfB30, zB3); zB3 = mfma16(a1, wfB31, zB3); zB3 = mfma16(a2, wfB32, zB3); zB3 = mfma16(a3, wfB33, zB3);

        f32x4 hvA, hvB;
        #pragma unroll
        for (int i = 0; i < 4; ++i) {
            float ig = sigm(zA0[i]);
            float fg = sigm(zA1[i]);
            float gg = fmaxf(zA2[i], 0.0f);
            float og = sigm(zA3[i]);
            cA[i] = fg * cA[i] + ig * gg;
            hvA[i] = og * fmaxf(cA[i], 0.0f);
        }
        #pragma unroll
        for (int i = 0; i < 4; ++i) {
            float ig = sigm(zB0[i]);
            float fg = sigm(zB1[i]);
            float gg = fmaxf(zB2[i], 0.0f);
            float og = sigm(zB3[i]);
            cB[i] = fg * cB[i] + ig * gg;
            hvB[i] = og * fmaxf(cB[i], 0.0f);
        }

        h16 a0h = (h16)hvA[0], a1h = (h16)hvA[1], a2h = (h16)hvA[2], a3h = (h16)hvA[3];
        h16 b0h = (h16)hvB[0], b1h = (h16)hvB[1], b2h = (h16)hvB[2], b3h = (h16)hvB[3];
        const int nb = (t & 1) ^ 1;
        hbuf[nb][r0 + 0][uA] = a0h; hbuf[nb][r0 + 1][uA] = a1h;
        hbuf[nb][r0 + 2][uA] = a2h; hbuf[nb][r0 + 3][uA] = a3h;
        hbuf[nb][r0 + 0][uB] = b0h; hbuf[nb][r0 + 1][uB] = b1h;
        hbuf[nb][r0 + 2][uB] = b2h; hbuf[nb][r0 + 3][uB] = b3h;

        hpA.x = pk2((float)a0h, (float)a1h); hpA.y = pk2((float)a2h, (float)a3h);
        hpB.x = pk2((float)b0h, (float)b1h); hpB.y = pk2((float)b2h, (float)b3h);
        if (do_hout) {
            *(uint2*)(hout + hobA + (uint)t * hstep) = hpA;   // async, never drained per-step
            *(uint2*)(hout + hobB + (uint)t * hstep) = hpB;
        }

        bar_lgkm();   // LDS-only ordering; vmem stays in flight
    }

    *(f32x4*)(cstate + coffA) = cA;
    *(f32x4*)(cstate + coffB) = cB;
    *(uint2*)(hstate + ((size_t)bt * KP + uA) * 16 + r0) = hpA;
    *(uint2*)(hstate + ((size_t)bt * KP + uB) * 16 + r0) = hpB;
}

// ================= head =================
__global__ void k_head(const h16* __restrict__ h2s, const float* __restrict__ Wd,
                       const float* __restrict__ bd, float* __restrict__ out)
{
    __shared__ float lg[OUT_];
    const int b = blockIdx.x, j = threadIdx.x;
    const int bt = b >> 4, r = b & 15;
    if (j < OUT_) {
        float acc = bd[j];
        for (int u = 0; u < H2_; ++u)
            acc += (float)h2s[((size_t)bt * KP + u) * 16 + r] * Wd[u * OUT_ + j];
        lg[j] = acc;
    }
    __syncthreads();
    if (j < OUT_) {
        float m = -1e30f;
        for (int k = 0; k < OUT_; ++k) m = fmaxf(m, lg[k]);
        float s = 0.0f;
        for (int k = 0; k < OUT_; ++k) s += expf(lg[k] - m);
        out[b * OUT_ + j] = expf(lg[j] - m) / s;
    }
}

// ================= R9 fallback (known-good) =================
#define G1_  400
#define G2_  512
#define FBTC 32
#define FB_XP1  0
#define FB_XP2  0
#define FB_WQ   51200
#define FB_XS   134400
#define FB_W2Q  32768
#define FB_H1C  139264
#define FB_U2Q  32768
#define FB_ZBUF 160000
#define FB_H1PK 162048
#define FB_H2PK 162256
#define FB_H2F  162512
#define FB_LDS  163328

__device__ __forceinline__ float fd2(uint wv, uint hv, float cc) {
#if __has_builtin(__builtin_amdgcn_fdot2)
    return __builtin_amdgcn_fdot2(__builtin_bit_cast(h16x2, wv),
                                  __builtin_bit_cast(h16x2, hv), cc, false);
#else
    h16x2 a = __builtin_bit_cast(h16x2, wv), b = __builtin_bit_cast(h16x2, hv);
    return cc + (float)a.x * (float)b.x + (float)a.y * (float)b.y;
#endif
}

__device__ __forceinline__ void stage_quads(const float* __restrict__ P, const int G,
                                            const int NQ, const int KREAL,
                                            char* dst, const int j)
{
    if (j < G) {
        for (int q = 0; q < NQ; ++q) {
            float f[8];
            #pragma unroll
            for (int r = 0; r < 8; ++r) {
                const int k = 8 * q + r;
                f[r] = (k < KREAL) ? P[(size_t)k * G + j] : 0.0f;
            }
            uint4 u;
            u.x = pk2(f[0], f[1]); u.y = pk2(f[2], f[3]);
            u.z = pk2(f[4], f[5]); u.w = pk2(f[6], f[7]);
            *(uint4*)(dst + (size_t)(q * G + j) * 16) = u;
        }
    }
}

__global__ __launch_bounds__(512) void lstm_fallback(
    const float* __restrict__ x,
    const float* __restrict__ W1, const float* __restrict__ U1, const float* __restrict__ b1,
    const float* __restrict__ W2, const float* __restrict__ U2, const float* __restrict__ b2,
    const float* __restrict__ Wd, const float* __restrict__ bd,
    float* __restrict__ out)
{
    __shared__ uint4 smem4[FB_LDS / 16];
    char* sm = (char*)smem4;
    const int b = blockIdx.x;
    const int j = threadIdx.x;
    float c1 = 0.0f, c2 = 0.0f;

    const uint u2r0 = pk2(U2[120 * G2_ + j], U2[121 * G2_ + j]);
    const uint u2r1 = pk2(U2[122 * G2_ + j], U2[123 * G2_ + j]);
    const uint u2r2 = pk2(U2[124 * G2_ + j], U2[125 * G2_ + j]);
    const uint u2r3 = pk2(U2[126 * G2_ + j], U2[127 * G2_ + j]);

    if (j < 52) *(uint*)(sm + FB_H1PK + 4 * j) = 0u;
    if (j < 64) *(uint*)(sm + FB_H2PK + 4 * j) = 0u;
    __syncthreads();

    const float* xrow = x + (size_t)b * T_ * F_;
    for (int ch = 0; ch < T_ / FBTC; ++ch) {
        stage_quads(W1, G1_, 8, 64, sm + FB_WQ, j);
        #pragma unroll
        for (int r = 0; r < 2; ++r) {
            int v = r * 512 + j;
            float2 xv = *(const float2*)(xrow + ch * (FBTC * F_) + 2 * v);
            *(uint*)(sm + FB_XS + 4 * v) = pk2(xv.x, xv.y);
        }
        __syncthreads();
        if (j < G1_) {
            const float bj = b1[j];
            const uint4* WQ = (const uint4*)(sm + FB_WQ);
            for (int t = 0; t < FBTC; ++t) {
                const uint4* XQ = (const uint4*)(sm + FB_XS + t * 128);
                float a0 = bj, a1 = 0.f, a2 = 0.f, a3 = 0.f;
                #pragma unroll
                for (int q = 0; q < 8; ++q) {
                    uint4 wq = WQ[q * G1_ + j]; uint4 hq = XQ[q];
                    a0 = fd2(wq.x, hq.x, a0); a1 = fd2(wq.y, hq.y, a1);
                    a2 = fd2(wq.z, hq.z, a2); a3 = fd2(wq.w, hq.w, a3);
                }
                *(float*)(sm + FB_XP1 + 4 * (t * G1_ + j)) = (a0 + a1) + (a2 + a3);
            }
        }
        __syncthreads();
        stage_quads(U1, G1_, 13, H1_, sm + FB_WQ, j);
        __syncthreads();
        for (int t = 0; t < FBTC; ++t) {
            if (j < G1_) {
                const uint4* WQ = (const uint4*)(sm + FB_WQ);
                const uint4* HP = (const uint4*)(sm + FB_H1PK);
                float a0 = *(const float*)(sm + FB_XP1 + 4 * (t * G1_ + j));
                float a1 = 0.f, a2 = 0.f, a3 = 0.f;
                #pragma unroll
                for (int q = 0; q < 13; ++q) {
                    uint4 wq = WQ[q * G1_ + j]; uint4 hq = HP[q];
                    a0 = fd2(wq.x, hq.x, a0); a1 = fd2(wq.y, hq.y, a1);
                    a2 = fd2(wq.z, hq.z, a2); a3 = fd2(wq.w, hq.w, a3);
                }
                *(float*)(sm + FB_ZBUF + 4 * j) = (a0 + a1) + (a2 + a3);
            }
            __syncthreads();
            if (j < H1_) {
                const float* zb = (const float*)(sm + FB_ZBUF);
                float ig = sigm(zb[j]);
                float fg = sigm(zb[H1_ + j]);
                float gg = fmaxf(zb[2 * H1_ + j], 0.0f);
                float og = sigm(zb[3 * H1_ + j]);
                c1 = fg * c1 + ig * gg;
                float h = og * fmaxf(c1, 0.0f);
                h16 hh = (h16)h;
                *(h16*)(sm + FB_H1PK + 2 * j) = hh;
                *(h16*)(sm + FB_H1C + t * 208 + 2 * j) = hh;
            }
            __syncthreads();
        }
        stage_quads(W2, G2_, 13, H1_, sm + FB_W2Q, j);
        __syncthreads();
        {
            const float bj = b2[j];
            const uint4* WQ = (const uint4*)(sm + FB_W2Q);
            for (int t = 0; t < FBTC; ++t) {
                const uint4* HC = (const uint4*)(sm + FB_H1C + t * 208);
                float a0 = bj, a1 = 0.f, a2 = 0.f, a3 = 0.f;
                #pragma unroll
                for (int q = 0; q < 13; ++q) {
                    uint4 wq = WQ[q * G2_ + j]; uint4 hq = HC[q];
                    a0 = fd2(wq.x, hq.x, a0); a1 = fd2(wq.y, hq.y, a1);
                    a2 = fd2(wq.z, hq.z, a2); a3 = fd2(wq.w, hq.w, a3);
                }
                *(h16*)(sm + FB_XP2 + 2 * (t * G2_ + j)) = (h16)((a0 + a1) + (a2 + a3));
            }
        }
        __syncthreads();
        stage_quads(U2, G2_, 15, 120, sm + FB_U2Q, j);
        __syncthreads();
        for (int t = 0; t < FBTC; ++t) {
            {
                const uint4* WQ = (const uint4*)(sm + FB_U2Q);
                const uint4* HP = (const uint4*)(sm + FB_H2PK);
                float a0 = (float)*(const h16*)(sm + FB_XP2 + 2 * (t * G2_ + j));
                float a1 = 0.f, a2 = 0.f, a3 = 0.f;
                #pragma unroll
                for (int q = 0; q < 15; ++q) {
                    uint4 wq = WQ[q * G2_ + j]; uint4 hq = HP[q];
                    a0 = fd2(wq.x, hq.x, a0); a1 = fd2(wq.y, hq.y, a1);
                    a2 = fd2(wq.z, hq.z, a2); a3 = fd2(wq.w, hq.w, a3);
                }
                uint4 hp15 = ((const uint4*)(sm + FB_H2PK))[15];
                a0 = fd2(u2r0, hp15.x, a0); a1 = fd2(u2r1, hp15.y, a1);
                a2 = fd2(u2r2, hp15.z, a2); a3 = fd2(u2r3, hp15.w, a3);
                *(float*)(sm + FB_ZBUF + 4 * j) = (a0 + a1) + (a2 + a3);
            }
            __syncthreads();
            if (j < H2_) {
                const float* zb = (const float*)(sm + FB_ZBUF);
                float ig = sigm(zb[j]);
                float fg = sigm(zb[H2_ + j]);
                float gg = fmaxf(zb[2 * H2_ + j], 0.0f);
                float og = sigm(zb[3 * H2_ + j]);
                c2 = fg * c2 + ig * gg;
                float h = og * fmaxf(c2, 0.0f);
                *(h16*)(sm + FB_H2PK + 2 * j) = (h16)h;
                *(float*)(sm + FB_H2F + 4 * j) = h;
            }
            __syncthreads();
        }
    }
    if (j < OUT_) {
        const float* h2 = (const float*)(sm + FB_H2F);
        float acc = bd[j];
        #pragma unroll
        for (int k = 0; k < H2_; ++k) acc += h2[k] * Wd[k * OUT_ + j];
        *(float*)(sm + FB_ZBUF + 4 * j) = acc;
    }
    __syncthreads();
    if (j < OUT_) {
        const float* zb = (const float*)(sm + FB_ZBUF);
        float m = -1e30f;
        for (int k = 0; k < OUT_; ++k) m = fmaxf(m, zb[k]);
        float s = 0.0f;
        for (int k = 0; k < OUT_; ++k) s += expf(zb[k] - m);
        out[b * OUT_ + j] = expf(zb[j] - m) / s;
    }
}

// ================= launcher =================
extern "C" void kernel_launch(void* const* d_in, const int* in_sizes, int n_in,
                              void* d_out, int out_size, void* d_ws, size_t ws_size,
                              hipStream_t stream) {
    const float* x  = (const float*)d_in[0];
    const float* W1 = (const float*)d_in[1];
    const float* U1 = (const float*)d_in[2];
    const float* b1 = (const float*)d_in[3];
    const float* W2 = (const float*)d_in[4];
    const float* U2 = (const float*)d_in[5];
    const float* b2 = (const float*)d_in[6];
    const float* Wd = (const float*)d_in[7];
    const float* bd = (const float*)d_in[8];
    float* out = (float*)d_out;

    if (ws_size >= WS_NEED) {
        char* ws = (char*)d_ws;
        h16*   xp  = (h16*)(ws + OFF_XP);
        h16*   h1g = (h16*)(ws + OFF_H1G);
        float* c1  = (float*)(ws + OFF_C1);
        float* c2  = (float*)(ws + OFF_C2);
        h16*   h1s = (h16*)(ws + OFF_H1S);
        h16*   h2s = (h16*)(ws + OFF_H2S);
        for (int ch = 0; ch < NCH; ++ch) {
            k_dense<0><<<128, 512, 0, stream>>>(x, (const h16*)nullptr, W1, b1, H1_, ch, xp);
            k_rec<<<16, 256, 0, stream>>>(U1, H1_, xp, h1g, 1, c1, h1s, ch);
            k_dense<1><<<128, 512, 0, stream>>>((const float*)nullptr, h1g, W2, b2, H2_, ch, xp);
            k_rec<<<16, 256, 0, stream>>>(U2, H2_, xp, (h16*)nullptr, 0, c2, h2s, ch);
        }
        k_head<<<256, 64, 0, stream>>>(h2s, Wd, bd, out);
    } else {
        lstm_fallback<<<B_, 512, 0, stream>>>(x, W1, U1, b1, W2, U2, b2, Wd, bd, out);
    }
}

// Round 14
// 1627.593 us; speedup vs baseline: 1.3001x; 1.3001x over previous
//
#include <hip/hip_runtime.h>
#include <math.h>

// Problem dims
#define B_   256
#define T_   512
#define F_   64
#define H1_  100
#define H2_  128
#define OUT_ 19
#define TCH  64             // timesteps per chunk (pipeline stage)
#define NCH  (T_/TCH)       // 8 chunks
#define NPC  512            // padded+permuted gate columns (both layers)
#define KP   128            // padded K (units) for both layers

typedef unsigned int uint;
typedef _Float16 h16;
typedef __attribute__((ext_vector_type(2))) _Float16 h16x2;
typedef __attribute__((ext_vector_type(8))) _Float16 f16x8;
typedef __attribute__((ext_vector_type(4))) float f32x4;

// ---- workspace layout (bytes) ----
// xp1, xp2 separate (pipeline: L1(ch+1) reads xp1 while L2(ch) reads xp2)
#define OFF_XP1w  0ull
#define XPW_BYTES (16ull*TCH*NPC*16*2)     // 16,777,216
#define OFF_XP2w  (OFF_XP1w + XPW_BYTES)
#define OFF_H1G   (OFF_XP2w + XPW_BYTES)
#define H1G_BYTES (16ull*TCH*KP*16*2)      // 4,194,304
#define OFF_C1    (OFF_H1G + H1G_BYTES)
#define CST_BYTES (16ull*KP*16*4)          // 131,072
#define OFF_C2    (OFF_C1 + CST_BYTES)
#define OFF_H1S   (OFF_C2 + CST_BYTES)
#define HST_BYTES (16ull*KP*16*2)          // 65,536
#define OFF_H2S   (OFF_H1S + HST_BYTES)
#define WS_NEED   (OFF_H2S + HST_BYTES)    // ~38.1 MB

__device__ __forceinline__ float sigm(float x) { return 1.0f / (1.0f + __expf(-x)); }

__device__ __forceinline__ uint pk2(float a, float b) {
    h16x2 h; h.x = (h16)a; h.y = (h16)b;
    return __builtin_bit_cast(uint, h);
}

__device__ __forceinline__ f32x4 mfma16(f16x8 a, f16x8 b, f32x4 c) {
    return __builtin_amdgcn_mfma_f32_16x16x32_f16(a, b, c, 0, 0, 0);
}

__device__ __forceinline__ f32x4 up4(uint2 v) {
    h16x2 a = __builtin_bit_cast(h16x2, v.x);
    h16x2 b = __builtin_bit_cast(h16x2, v.y);
    f32x4 r; r[0] = (float)a.x; r[1] = (float)a.y; r[2] = (float)b.x; r[3] = (float)b.y;
    return r;
}

// B-fragment loader with gate-column permutation.
__device__ __forceinline__ f16x8 load_bfrag(const float* __restrict__ P, int H, int OG,
                                            int Kreal, int ubase, int g, int q, int lane) {
    const int u  = ubase + (lane & 15);
    const int k0 = q * 32 + (lane >> 4) * 8;
    const int col = g * H + u;
    float f[8];
    #pragma unroll
    for (int e = 0; e < 8; ++e) {
        const int k = k0 + e;
        f[e] = (u < H && k < Kreal) ? P[(size_t)k * OG + col] : 0.0f;
    }
    uint4 r;
    r.x = pk2(f[0], f[1]); r.y = pk2(f[2], f[3]);
    r.z = pk2(f[4], f[5]); r.w = pk2(f[6], f[7]);
    return __builtin_bit_cast(f16x8, r);
}

// ================= dense pre-projection GEMM =================
// grid = TCH blocks x 512 thr; block handles 16 M-tiles.
template<int MODE>
__global__ __launch_bounds__(512) void k_dense(
    const float* __restrict__ Af, const h16* __restrict__ Ah,
    const float* __restrict__ W, const float* __restrict__ bias,
    const int H, const int ch, h16* __restrict__ xp)
{
    const int j = threadIdx.x, lane = j & 63, w = j >> 6;
    const int KF = MODE ? 4 : 2;
    const int KREAL = MODE ? 100 : 64;
    const int OG = 4 * H;

    f16x8 bf[4][4];
    #pragma unroll
    for (int g = 0; g < 4; ++g)
        #pragma unroll
        for (int q = 0; q < 4; ++q)
            if (q < KF) bf[g][q] = load_bfrag(W, H, OG, KREAL, w * 16, g, q, lane);

    float bv[4];
    #pragma unroll
    for (int g = 0; g < 4; ++g) {
        const int u = w * 16 + (lane & 15);
        bv[g] = (u < H) ? bias[g * H + u] : 0.0f;
    }

    const int ci = lane & 15, hi = lane >> 4;
    for (int it = 0; it < 16; ++it) {
        const int m = blockIdx.x * 16 + it;
        const int bt = m / TCH, tc = m % TCH;

        f16x8 af[4];
        if (MODE == 0) {
            const int b = bt * 16 + ci;
            const int t = ch * TCH + tc;
            #pragma unroll
            for (int q = 0; q < 2; ++q) {
                const int k0 = q * 32 + hi * 8;
                const float* p = Af + ((size_t)b * T_ + t) * F_ + k0;
                float4 x0 = *(const float4*)p;
                float4 x1 = *(const float4*)(p + 4);
                uint4 r;
                r.x = pk2(x0.x, x0.y); r.y = pk2(x0.z, x0.w);
                r.z = pk2(x1.x, x1.y); r.w = pk2(x1.z, x1.w);
                af[q] = __builtin_bit_cast(f16x8, r);
            }
        } else {
            #pragma unroll
            for (int q = 0; q < 4; ++q) {
                const int k0 = q * 32 + hi * 8;
                const size_t base = ((size_t)(bt * TCH + tc) * KP + k0) * 16 + ci;
                f16x8 a;
                #pragma unroll
                for (int e = 0; e < 8; ++e) a[e] = Ah[base + (size_t)e * 16];
                af[q] = a;
            }
        }

        f32x4 acc[4];
        #pragma unroll
        for (int g = 0; g < 4; ++g) { acc[g][0]=bv[g]; acc[g][1]=bv[g]; acc[g][2]=bv[g]; acc[g][3]=bv[g]; }
        #pragma unroll
        for (int g = 0; g < 4; ++g)
            #pragma unroll
            for (int q = 0; q < 4; ++q)
                if (q < KF) acc[g] = mfma16(af[q], bf[g][q], acc[g]);

        #pragma unroll
        for (int g = 0; g < 4; ++g) {
            const int c = (w * 4 + g) * 16 + ci;
            const size_t o = ((size_t)(bt * TCH + tc) * NPC + c) * 16 + hi * 4;
            uint2 s;
            s.x = pk2(acc[g][0], acc[g][1]);
            s.y = pk2(acc[g][2], acc[g][3]);
            *(uint2*)(xp + o) = s;
        }
    }
}

// ================= recurrence body (R11's 8-wave version, TCH=64) =================
#define LF(G,Q) f16x8 wf##G##Q = load_bfrag(U, H, 4*H, H, w * 16, G, Q, lane); \
                asm volatile("" ::: "memory");

__device__ __forceinline__ void rec_body(
    const float* __restrict__ U, const int H,
    const h16* __restrict__ xp, h16* __restrict__ hout, const int do_hout,
    float* __restrict__ cstate, h16* __restrict__ hstate, const int ch,
    const int bt, const int j)
{
    __shared__ h16 hbuf[2][16][136];   // [buf][batch-row][unit], 272B row stride
    const int lane = j & 63, w = j >> 6;
    const int ci = lane & 15, hi = lane >> 4;
    const int myu = w * 16 + ci;
    const int r0 = hi * 4;

    LF(0,0) LF(0,1) LF(0,2) LF(0,3)
    LF(1,0) LF(1,1) LF(1,2) LF(1,3)
    LF(2,0) LF(2,1) LF(2,2) LF(2,3)
    LF(3,0) LF(3,1) LF(3,2) LF(3,3)

    // init hbuf[0] with carried h state (or zeros)
    {
        const int u = j & 127, rr = (j >> 7) * 4;
        #pragma unroll
        for (int i = 0; i < 4; ++i) {
            h16 v = (h16)0.0f;
            if (ch != 0) v = hstate[((size_t)bt * KP + u) * 16 + rr + i];
            hbuf[0][rr + i][u] = v;
        }
    }
    // carried c state
    f32x4 c;
    const size_t coff = ((size_t)bt * KP + myu) * 16 + r0;
    if (ch == 0) { c[0]=0.f; c[1]=0.f; c[2]=0.f; c[3]=0.f; }
    else         { c = *(const f32x4*)(cstate + coff); }
    __syncthreads();

    const uint xstep = NPC * 16;
    uint xb0 = (uint)(((size_t)bt * TCH) * NPC + (w * 64 + ci)) * 16 + r0;
    uint xb1 = xb0 + 16 * 16, xb2 = xb0 + 32 * 16, xb3 = xb0 + 48 * 16;
    uint2 xn0 = *(const uint2*)(xp + xb0);
    uint2 xn1 = *(const uint2*)(xp + xb1);
    uint2 xn2 = *(const uint2*)(xp + xb2);
    uint2 xn3 = *(const uint2*)(xp + xb3);

    const uint hstep = KP * 16;
    uint hob = (uint)(((size_t)bt * TCH) * KP + myu) * 16 + r0;

    uint2 hp; hp.x = 0u; hp.y = 0u;

    for (int t = 0; t < TCH; ++t) {
        const h16* hb = &hbuf[t & 1][0][0];
        f16x8 a0 = *(const f16x8*)(hb + ci * 136 + 0  + hi * 8);
        f16x8 a1 = *(const f16x8*)(hb + ci * 136 + 32 + hi * 8);
        f16x8 a2 = *(const f16x8*)(hb + ci * 136 + 64 + hi * 8);
        f16x8 a3 = *(const f16x8*)(hb + ci * 136 + 96 + hi * 8);

        f32x4 z0 = up4(xn0), z1 = up4(xn1), z2 = up4(xn2), z3 = up4(xn3);

        const int tn = (t + 1 < TCH) ? t + 1 : t;
        xn0 = *(const uint2*)(xp + xb0 + (uint)tn * xstep);
        xn1 = *(const uint2*)(xp + xb1 + (uint)tn * xstep);
        xn2 = *(const uint2*)(xp + xb2 + (uint)tn * xstep);
        xn3 = *(const uint2*)(xp + xb3 + (uint)tn * xstep);

        z0 = mfma16(a0, wf00, z0); z0 = mfma16(a1, wf01, z0); z0 = mfma16(a2, wf02, z0); z0 = mfma16(a3, wf03, z0);
        z1 = mfma16(a0, wf10, z1); z1 = mfma16(a1, wf11, z1); z1 = mfma16(a2, wf12, z1); z1 = mfma16(a3, wf13, z1);
        z2 = mfma16(a0, wf20, z2); z2 = mfma16(a1, wf21, z2); z2 = mfma16(a2, wf22, z2); z2 = mfma16(a3, wf23, z2);
        z3 = mfma16(a0, wf30, z3); z3 = mfma16(a1, wf31, z3); z3 = mfma16(a2, wf32, z3); z3 = mfma16(a3, wf33, z3);

        f32x4 hv;
        #pragma unroll
        for (int i = 0; i < 4; ++i) {
            float ig = sigm(z0[i]);
            float fg = sigm(z1[i]);
            float gg = fmaxf(z2[i], 0.0f);
            float og = sigm(z3[i]);
            c[i] = fg * c[i] + ig * gg;
            hv[i] = og * fmaxf(c[i], 0.0f);
        }
        h16 h0 = (h16)hv[0], h1 = (h16)hv[1], h2 = (h16)hv[2], h3 = (h16)hv[3];
        hbuf[(t & 1) ^ 1][r0 + 0][myu] = h0;
        hbuf[(t & 1) ^ 1][r0 + 1][myu] = h1;
        hbuf[(t & 1) ^ 1][r0 + 2][myu] = h2;
        hbuf[(t & 1) ^ 1][r0 + 3][myu] = h3;

        h16x2 p01; p01.x = h0; p01.y = h1;
        h16x2 p23; p23.x = h2; p23.y = h3;
        hp.x = __builtin_bit_cast(uint, p01);
        hp.y = __builtin_bit_cast(uint, p23);
        if (do_hout) *(uint2*)(hout + hob + (uint)t * hstep) = hp;

        __syncthreads();
    }

    *(f32x4*)(cstate + coff) = c;
    *(uint2*)(hstate + ((size_t)bt * KP + myu) * 16 + r0) = hp;
}

__global__ __launch_bounds__(512) void k_rec_single(
    const float* __restrict__ U, const int H,
    const h16* __restrict__ xp, h16* __restrict__ hout, const int do_hout,
    float* __restrict__ cstate, h16* __restrict__ hstate, const int ch)
{
    rec_body(U, H, xp, hout, do_hout, cstate, hstate, ch, blockIdx.x, threadIdx.x);
}

// blocks 0-15: role A (layer-2, chunk chA). blocks 16-31: role B (layer-1, chunk chB).
__global__ __launch_bounds__(512) void k_rec_pair(
    const float* __restrict__ UA, const int HA, const h16* __restrict__ xpA,
    h16* __restrict__ houtA, const int dohA, float* __restrict__ csA,
    h16* __restrict__ hsA, const int chA,
    const float* __restrict__ UB, const int HB, const h16* __restrict__ xpB,
    h16* __restrict__ houtB, const int dohB, float* __restrict__ csB,
    h16* __restrict__ hsB, const int chB)
{
    const int role = blockIdx.x >> 4;
    const int bt = blockIdx.x & 15;
    const float* U   = role ? UB : UA;
    const int    H   = role ? HB : HA;
    const h16*   xp  = role ? xpB : xpA;
    h16*         ho  = role ? houtB : houtA;
    const int    doh = role ? dohB : dohA;
    float*       cs  = role ? csB : csA;
    h16*         hs  = role ? hsB : hsA;
    const int    ch  = role ? chB : chA;
    rec_body(U, H, xp, ho, doh, cs, hs, ch, bt, threadIdx.x);
}

// ================= head =================
__global__ void k_head(const h16* __restrict__ h2s, const float* __restrict__ Wd,
                       const float* __restrict__ bd, float* __restrict__ out)
{
    __shared__ float lg[OUT_];
    const int b = blockIdx.x, j = threadIdx.x;
    const int bt = b >> 4, r = b & 15;
    if (j < OUT_) {
        float acc = bd[j];
        for (int u = 0; u < H2_; ++u)
            acc += (float)h2s[((size_t)bt * KP + u) * 16 + r] * Wd[u * OUT_ + j];
        lg[j] = acc;
    }
    __syncthreads();
    if (j < OUT_) {
        float m = -1e30f;
        for (int k = 0; k < OUT_; ++k) m = fmaxf(m, lg[k]);
        float s = 0.0f;
        for (int k = 0; k < OUT_; ++k) s += expf(lg[k] - m);
        out[b * OUT_ + j] = expf(lg[j] - m) / s;
    }
}

// ================= R9 fallback (known-good) =================
#define G1_  400
#define G2_  512
#define FBTC 32
#define FB_XP1  0
#define FB_XP2  0
#define FB_WQ   51200
#define FB_XS   134400
#define FB_W2Q  32768
#define FB_H1C  139264
#define FB_U2Q  32768
#define FB_ZBUF 160000
#define FB_H1PK 162048
#define FB_H2PK 162256
#define FB_H2F  162512
#define FB_LDS  163328

__device__ __forceinline__ float fd2(uint wv, uint hv, float cc) {
#if __has_builtin(__builtin_amdgcn_fdot2)
    return __builtin_amdgcn_fdot2(__builtin_bit_cast(h16x2, wv),
                                  __builtin_bit_cast(h16x2, hv), cc, false);
#else
    h16x2 a = __builtin_bit_cast(h16x2, wv), b = __builtin_bit_cast(h16x2, hv);
    return cc + (float)a.x * (float)b.x + (float)a.y * (float)b.y;
#endif
}

__device__ __forceinline__ void stage_quads(const float* __restrict__ P, const int G,
                                            const int NQ, const int KREAL,
                                            char* dst, const int j)
{
    if (j < G) {
        for (int q = 0; q < NQ; ++q) {
            float f[8];
            #pragma unroll
            for (int r = 0; r < 8; ++r) {
                const int k = 8 * q + r;
                f[r] = (k < KREAL) ? P[(size_t)k * G + j] : 0.0f;
            }
            uint4 u;
            u.x = pk2(f[0], f[1]); u.y = pk2(f[2], f[3]);
            u.z = pk2(f[4], f[5]); u.w = pk2(f[6], f[7]);
            *(uint4*)(dst + (size_t)(q * G + j) * 16) = u;
        }
    }
}

__global__ __launch_bounds__(512) void lstm_fallback(
    const float* __restrict__ x,
    const float* __restrict__ W1, const float* __restrict__ U1, const float* __restrict__ b1,
    const float* __restrict__ W2, const float* __restrict__ U2, const float* __restrict__ b2,
    const float* __restrict__ Wd, const float* __restrict__ bd,
    float* __restrict__ out)
{
    __shared__ uint4 smem4[FB_LDS / 16];
    char* sm = (char*)smem4;
    const int b = blockIdx.x;
    const int j = threadIdx.x;
    float c1 = 0.0f, c2 = 0.0f;

    const uint u2r0 = pk2(U2[120 * G2_ + j], U2[121 * G2_ + j]);
    const uint u2r1 = pk2(U2[122 * G2_ + j], U2[123 * G2_ + j]);
    const uint u2r2 = pk2(U2[124 * G2_ + j], U2[125 * G2_ + j]);
    const uint u2r3 = pk2(U2[126 * G2_ + j], U2[127 * G2_ + j]);

    if (j < 52) *(uint*)(sm + FB_H1PK + 4 * j) = 0u;
    if (j < 64) *(uint*)(sm + FB_H2PK + 4 * j) = 0u;
    __syncthreads();

    const float* xrow = x + (size_t)b * T_ * F_;
    for (int ch = 0; ch < T_ / FBTC; ++ch) {
        stage_quads(W1, G1_, 8, 64, sm + FB_WQ, j);
        #pragma unroll
        for (int r = 0; r < 2; ++r) {
            int v = r * 512 + j;
            float2 xv = *(const float2*)(xrow + ch * (FBTC * F_) + 2 * v);
            *(uint*)(sm + FB_XS + 4 * v) = pk2(xv.x, xv.y);
        }
        __syncthreads();
        if (j < G1_) {
            const float bj = b1[j];
            const uint4* WQ = (const uint4*)(sm + FB_WQ);
            for (int t = 0; t < FBTC; ++t) {
                const uint4* XQ = (const uint4*)(sm + FB_XS + t * 128);
                float a0 = bj, a1 = 0.f, a2 = 0.f, a3 = 0.f;
                #pragma unroll
                for (int q = 0; q < 8; ++q) {
                    uint4 wq = WQ[q * G1_ + j]; uint4 hq = XQ[q];
                    a0 = fd2(wq.x, hq.x, a0); a1 = fd2(wq.y, hq.y, a1);
                    a2 = fd2(wq.z, hq.z, a2); a3 = fd2(wq.w, hq.w, a3);
                }
                *(float*)(sm + FB_XP1 + 4 * (t * G1_ + j)) = (a0 + a1) + (a2 + a3);
            }
        }
        __syncthreads();
        stage_quads(U1, G1_, 13, H1_, sm + FB_WQ, j);
        __syncthreads();
        for (int t = 0; t < FBTC; ++t) {
            if (j < G1_) {
                const uint4* WQ = (const uint4*)(sm + FB_WQ);
                const uint4* HP = (const uint4*)(sm + FB_H1PK);
                float a0 = *(const float*)(sm + FB_XP1 + 4 * (t * G1_ + j));
                float a1 = 0.f, a2 = 0.f, a3 = 0.f;
                #pragma unroll
                for (int q = 0; q < 13; ++q) {
                    uint4 wq = WQ[q * G1_ + j]; uint4 hq = HP[q];
                    a0 = fd2(wq.x, hq.x, a0); a1 = fd2(wq.y, hq.y, a1);
                    a2 = fd2(wq.z, hq.z, a2); a3 = fd2(wq.w, hq.w, a3);
                }
                *(float*)(sm + FB_ZBUF + 4 * j) = (a0 + a1) + (a2 + a3);
            }
            __syncthreads();
            if (j < H1_) {
                const float* zb = (const float*)(sm + FB_ZBUF);
                float ig = sigm(zb[j]);
                float fg = sigm(zb[H1_ + j]);
                float gg = fmaxf(zb[2 * H1_ + j], 0.0f);
                float og = sigm(zb[3 * H1_ + j]);
                c1 = fg * c1 + ig * gg;
                float h = og * fmaxf(c1, 0.0f);
                h16 hh = (h16)h;
                *(h16*)(sm + FB_H1PK + 2 * j) = hh;
                *(h16*)(sm + FB_H1C + t * 208 + 2 * j) = hh;
            }
            __syncthreads();
        }
        stage_quads(W2, G2_, 13, H1_, sm + FB_W2Q, j);
        __syncthreads();
        {
            const float bj = b2[j];
            const uint4* WQ = (const uint4*)(sm + FB_W2Q);
            for (int t = 0; t < FBTC; ++t) {
                const uint4* HC = (const uint4*)(sm + FB_H1C + t * 208);
                float a0 = bj, a1 = 0.f, a2 = 0.f, a3 = 0.f;
                #pragma unroll
                for (int q = 0; q < 13; ++q) {
                    uint4 wq = WQ[q * G2_ + j]; uint4 hq = HC[q];
                    a0 = fd2(wq.x, hq.x, a0); a1 = fd2(wq.y, hq.y, a1);
                    a2 = fd2(wq.z, hq.z, a2); a3 = fd2(wq.w, hq.w, a3);
                }
                *(h16*)(sm + FB_XP2 + 2 * (t * G2_ + j)) = (h16)((a0 + a1) + (a2 + a3));
            }
        }
        __syncthreads();
        stage_quads(U2, G2_, 15, 120, sm + FB_U2Q, j);
        __syncthreads();
        for (int t = 0; t < FBTC; ++t) {
            {
                const uint4* WQ = (const uint4*)(sm + FB_U2Q);
                const uint4* HP = (const uint4*)(sm + FB_H2PK);
                float a0 = (float)*(const h16*)(sm + FB_XP2 + 2 * (t * G2_ + j));
                float a1 = 0.f, a2 = 0.f, a3 = 0.f;
                #pragma unroll
                for (int q = 0; q < 15; ++q) {
                    uint4 wq = WQ[q * G2_ + j]; uint4 hq = HP[q];
                    a0 = fd2(wq.x, hq.x, a0); a1 = fd2(wq.y, hq.y, a1);
                    a2 = fd2(wq.z, hq.z, a2); a3 = fd2(wq.w, hq.w, a3);
                }
                uint4 hp15 = ((const uint4*)(sm + FB_H2PK))[15];
                a0 = fd2(u2r0, hp15.x, a0); a1 = fd2(u2r1, hp15.y, a1);
                a2 = fd2(u2r2, hp15.z, a2); a3 = fd2(u2r3, hp15.w, a3);
                *(float*)(sm + FB_ZBUF + 4 * j) = (a0 + a1) + (a2 + a3);
            }
            __syncthreads();
            if (j < H2_) {
                const float* zb = (const float*)(sm + FB_ZBUF);
                float ig = sigm(zb[j]);
                float fg = sigm(zb[H2_ + j]);
                float gg = fmaxf(zb[2 * H2_ + j], 0.0f);
                float og = sigm(zb[3 * H2_ + j]);
                c2 = fg * c2 + ig * gg;
                float h = og * fmaxf(c2, 0.0f);
                *(h16*)(sm + FB_H2PK + 2 * j) = (h16)h;
                *(float*)(sm + FB_H2F + 4 * j) = h;
            }
            __syncthreads();
        }
    }
    if (j < OUT_) {
        const float* h2 = (const float*)(sm + FB_H2F);
        float acc = bd[j];
        #pragma unroll
        for (int k = 0; k < H2_; ++k) acc += h2[k] * Wd[k * OUT_ + j];
        *(float*)(sm + FB_ZBUF + 4 * j) = acc;
    }
    __syncthreads();
    if (j < OUT_) {
        const float* zb = (const float*)(sm + FB_ZBUF);
        float m = -1e30f;
        for (int k = 0; k < OUT_; ++k) m = fmaxf(m, zb[k]);
        float s = 0.0f;
        for (int k = 0; k < OUT_; ++k) s += expf(zb[k] - m);
        out[b * OUT_ + j] = expf(zb[j] - m) / s;
    }
}

// ================= launcher =================
extern "C" void kernel_launch(void* const* d_in, const int* in_sizes, int n_in,
                              void* d_out, int out_size, void* d_ws, size_t ws_size,
                              hipStream_t stream) {
    const float* x  = (const float*)d_in[0];
    const float* W1 = (const float*)d_in[1];
    const float* U1 = (const float*)d_in[2];
    const float* b1 = (const float*)d_in[3];
    const float* W2 = (const float*)d_in[4];
    const float* U2 = (const float*)d_in[5];
    const float* b2 = (const float*)d_in[6];
    const float* Wd = (const float*)d_in[7];
    const float* bd = (const float*)d_in[8];
    float* out = (float*)d_out;

    if (ws_size >= WS_NEED) {
        char* ws = (char*)d_ws;
        h16*   xp1 = (h16*)(ws + OFF_XP1w);
        h16*   xp2 = (h16*)(ws + OFF_XP2w);
        h16*   h1g = (h16*)(ws + OFF_H1G);
        float* c1  = (float*)(ws + OFF_C1);
        float* c2  = (float*)(ws + OFF_C2);
        h16*   h1s = (h16*)(ws + OFF_H1S);
        h16*   h2s = (h16*)(ws + OFF_H2S);

        // prologue: dense1(0) ; rec1(0)
        k_dense<0><<<TCH, 512, 0, stream>>>(x, (const h16*)nullptr, W1, b1, H1_, 0, xp1);
        k_rec_single<<<16, 512, 0, stream>>>(U1, H1_, xp1, h1g, 1, c1, h1s, 0);

        for (int ch = 0; ch < NCH; ++ch) {
            // dense2(ch) consumes h1g(ch); dense1(ch+1) refills xp1
            k_dense<1><<<TCH, 512, 0, stream>>>((const float*)nullptr, h1g, W2, b2, H2_, ch, xp2);
            if (ch + 1 < NCH) {
                k_dense<0><<<TCH, 512, 0, stream>>>(x, (const h16*)nullptr, W1, b1, H1_, ch + 1, xp1);
                // concurrent: rec2(ch) on blocks 0-15, rec1(ch+1) on blocks 16-31
                k_rec_pair<<<32, 512, 0, stream>>>(
                    U2, H2_, xp2, (h16*)nullptr, 0, c2, h2s, ch,
                    U1, H1_, xp1, h1g,           1, c1, h1s, ch + 1);
            } else {
                k_rec_single<<<16, 512, 0, stream>>>(U2, H2_, xp2, (h16*)nullptr, 0, c2, h2s, ch);
            }
        }
        k_head<<<256, 64, 0, stream>>>(h2s, Wd, bd, out);
    } else {
        lstm_fallback<<<B_, 512, 0, stream>>>(x, W1, U1, b1, W2, U2, b2, Wd, bd, out);
    }
}

// Round 15
// 1270.821 us; speedup vs baseline: 1.6651x; 1.2807x over previous
//
#include <hip/hip_runtime.h>
#include <math.h>

// Problem dims
#define B_   256
#define T_   512
#define F_   64
#define H1_  100
#define H2_  128
#define OUT_ 19
#define TCH  64             // timesteps per chunk (pipeline stage)
#define NCH  (T_/TCH)       // 8 chunks
#define NPC  512            // padded+permuted gate columns (both layers)
#define KP   128            // padded K (units) for both layers

typedef unsigned int uint;
typedef _Float16 h16;
typedef __attribute__((ext_vector_type(2))) _Float16 h16x2;
typedef __attribute__((ext_vector_type(8))) _Float16 f16x8;
typedef __attribute__((ext_vector_type(4))) float f32x4;

// ---- workspace layouts (bytes) ----
#define XPW_BYTES (16ull*TCH*NPC*16*2)     // 16,777,216 per xp buffer
#define H1G_BYTES (16ull*TCH*KP*16*2)      // 4,194,304
#define CST_BYTES (16ull*KP*16*4)          // 131,072
#define HST_BYTES (16ull*KP*16*2)          // 65,536

// FULL tier: xp1 double-buffered (dense1 folded into rec dispatches)
#define F_XP1A  0ull
#define F_XP1B  (F_XP1A + XPW_BYTES)
#define F_XP2   (F_XP1B + XPW_BYTES)
#define F_H1G   (F_XP2  + XPW_BYTES)
#define F_C1    (F_H1G  + H1G_BYTES)
#define F_C2    (F_C1   + CST_BYTES)
#define F_H1S   (F_C2   + CST_BYTES)
#define F_H2S   (F_H1S  + HST_BYTES)
#define WS_FULL (F_H2S  + HST_BYTES)       // ~54.9 MB

// MID tier (R14 schedule): single xp1
#define M_XP1   0ull
#define M_XP2   (M_XP1 + XPW_BYTES)
#define M_H1G   (M_XP2 + XPW_BYTES)
#define M_C1    (M_H1G + H1G_BYTES)
#define M_C2    (M_C1  + CST_BYTES)
#define M_H1S   (M_C2  + CST_BYTES)
#define M_H2S   (M_H1S + HST_BYTES)
#define WS_MID  (M_H2S + HST_BYTES)        // ~38.1 MB

__device__ __forceinline__ float sigm(float x) { return 1.0f / (1.0f + __expf(-x)); }

__device__ __forceinline__ uint pk2(float a, float b) {
    h16x2 h; h.x = (h16)a; h.y = (h16)b;
    return __builtin_bit_cast(uint, h);
}

__device__ __forceinline__ f32x4 mfma16(f16x8 a, f16x8 b, f32x4 c) {
    return __builtin_amdgcn_mfma_f32_16x16x32_f16(a, b, c, 0, 0, 0);
}

__device__ __forceinline__ f32x4 up4(uint2 v) {
    h16x2 a = __builtin_bit_cast(h16x2, v.x);
    h16x2 b = __builtin_bit_cast(h16x2, v.y);
    f32x4 r; r[0] = (float)a.x; r[1] = (float)a.y; r[2] = (float)b.x; r[3] = (float)b.y;
    return r;
}

// B-fragment loader with gate-column permutation.
__device__ __forceinline__ f16x8 load_bfrag(const float* __restrict__ P, int H, int OG,
                                            int Kreal, int ubase, int g, int q, int lane) {
    const int u  = ubase + (lane & 15);
    const int k0 = q * 32 + (lane >> 4) * 8;
    const int col = g * H + u;
    float f[8];
    #pragma unroll
    for (int e = 0; e < 8; ++e) {
        const int k = k0 + e;
        f[e] = (u < H && k < Kreal) ? P[(size_t)k * OG + col] : 0.0f;
    }
    uint4 r;
    r.x = pk2(f[0], f[1]); r.y = pk2(f[2], f[3]);
    r.z = pk2(f[4], f[5]); r.w = pk2(f[6], f[7]);
    return __builtin_bit_cast(f16x8, r);
}

// ================= dense pre-projection body =================
// NIT M-tiles per block; grid = 1024/NIT blocks.
template<int MODE, int NIT>
__device__ __forceinline__ void dense_body(
    const float* __restrict__ Af, const h16* __restrict__ Ah,
    const float* __restrict__ W, const float* __restrict__ bias,
    const int H, const int ch, h16* __restrict__ xp,
    const int bid, const int j)
{
    const int lane = j & 63, w = j >> 6;
    const int KF = MODE ? 4 : 2;
    const int KREAL = MODE ? 100 : 64;
    const int OG = 4 * H;

    f16x8 bf[4][4];
    #pragma unroll
    for (int g = 0; g < 4; ++g)
        #pragma unroll
        for (int q = 0; q < 4; ++q)
            if (q < KF) bf[g][q] = load_bfrag(W, H, OG, KREAL, w * 16, g, q, lane);

    float bv[4];
    #pragma unroll
    for (int g = 0; g < 4; ++g) {
        const int u = w * 16 + (lane & 15);
        bv[g] = (u < H) ? bias[g * H + u] : 0.0f;
    }

    const int ci = lane & 15, hi = lane >> 4;
    #pragma unroll
    for (int it = 0; it < NIT; ++it) {
        const int m = bid * NIT + it;
        const int bt = m / TCH, tc = m % TCH;

        f16x8 af[4];
        if (MODE == 0) {
            const int b = bt * 16 + ci;
            const int t = ch * TCH + tc;
            #pragma unroll
            for (int q = 0; q < 2; ++q) {
                const int k0 = q * 32 + hi * 8;
                const float* p = Af + ((size_t)b * T_ + t) * F_ + k0;
                float4 x0 = *(const float4*)p;
                float4 x1 = *(const float4*)(p + 4);
                uint4 r;
                r.x = pk2(x0.x, x0.y); r.y = pk2(x0.z, x0.w);
                r.z = pk2(x1.x, x1.y); r.w = pk2(x1.z, x1.w);
                af[q] = __builtin_bit_cast(f16x8, r);
            }
        } else {
            #pragma unroll
            for (int q = 0; q < 4; ++q) {
                const int k0 = q * 32 + hi * 8;
                const size_t base = ((size_t)(bt * TCH + tc) * KP + k0) * 16 + ci;
                f16x8 a;
                #pragma unroll
                for (int e = 0; e < 8; ++e) a[e] = Ah[base + (size_t)e * 16];
                af[q] = a;
            }
        }

        f32x4 acc[4];
        #pragma unroll
        for (int g = 0; g < 4; ++g) { acc[g][0]=bv[g]; acc[g][1]=bv[g]; acc[g][2]=bv[g]; acc[g][3]=bv[g]; }
        #pragma unroll
        for (int g = 0; g < 4; ++g)
            #pragma unroll
            for (int q = 0; q < 4; ++q)
                if (q < KF) acc[g] = mfma16(af[q], bf[g][q], acc[g]);

        #pragma unroll
        for (int g = 0; g < 4; ++g) {
            const int c = (w * 4 + g) * 16 + ci;
            const size_t o = ((size_t)(bt * TCH + tc) * NPC + c) * 16 + hi * 4;
            uint2 s;
            s.x = pk2(acc[g][0], acc[g][1]);
            s.y = pk2(acc[g][2], acc[g][3]);
            *(uint2*)(xp + o) = s;
        }
    }
}

template<int MODE, int NIT>
__global__ __launch_bounds__(512) void k_dense(
    const float* __restrict__ Af, const h16* __restrict__ Ah,
    const float* __restrict__ W, const float* __restrict__ bias,
    const int H, const int ch, h16* __restrict__ xp)
{
    dense_body<MODE, NIT>(Af, Ah, W, bias, H, ch, xp, blockIdx.x, threadIdx.x);
}

// ================= recurrence body (R14, unchanged) =================
#define LF(G,Q) f16x8 wf##G##Q = load_bfrag(U, H, 4*H, H, w * 16, G, Q, lane); \
                asm volatile("" ::: "memory");

__device__ __forceinline__ void rec_body(
    const float* __restrict__ U, const int H,
    const h16* __restrict__ xp, h16* __restrict__ hout, const int do_hout,
    float* __restrict__ cstate, h16* __restrict__ hstate, const int ch,
    const int bt, const int j)
{
    __shared__ h16 hbuf[2][16][136];
    const int lane = j & 63, w = j >> 6;
    const int ci = lane & 15, hi = lane >> 4;
    const int myu = w * 16 + ci;
    const int r0 = hi * 4;

    LF(0,0) LF(0,1) LF(0,2) LF(0,3)
    LF(1,0) LF(1,1) LF(1,2) LF(1,3)
    LF(2,0) LF(2,1) LF(2,2) LF(2,3)
    LF(3,0) LF(3,1) LF(3,2) LF(3,3)

    {
        const int u = j & 127, rr = (j >> 7) * 4;
        #pragma unroll
        for (int i = 0; i < 4; ++i) {
            h16 v = (h16)0.0f;
            if (ch != 0) v = hstate[((size_t)bt * KP + u) * 16 + rr + i];
            hbuf[0][rr + i][u] = v;
        }
    }
    f32x4 c;
    const size_t coff = ((size_t)bt * KP + myu) * 16 + r0;
    if (ch == 0) { c[0]=0.f; c[1]=0.f; c[2]=0.f; c[3]=0.f; }
    else         { c = *(const f32x4*)(cstate + coff); }
    __syncthreads();

    const uint xstep = NPC * 16;
    uint xb0 = (uint)(((size_t)bt * TCH) * NPC + (w * 64 + ci)) * 16 + r0;
    uint xb1 = xb0 + 16 * 16, xb2 = xb0 + 32 * 16, xb3 = xb0 + 48 * 16;
    uint2 xn0 = *(const uint2*)(xp + xb0);
    uint2 xn1 = *(const uint2*)(xp + xb1);
    uint2 xn2 = *(const uint2*)(xp + xb2);
    uint2 xn3 = *(const uint2*)(xp + xb3);

    const uint hstep = KP * 16;
    uint hob = (uint)(((size_t)bt * TCH) * KP + myu) * 16 + r0;

    uint2 hp; hp.x = 0u; hp.y = 0u;

    for (int t = 0; t < TCH; ++t) {
        const h16* hb = &hbuf[t & 1][0][0];
        f16x8 a0 = *(const f16x8*)(hb + ci * 136 + 0  + hi * 8);
        f16x8 a1 = *(const f16x8*)(hb + ci * 136 + 32 + hi * 8);
        f16x8 a2 = *(const f16x8*)(hb + ci * 136 + 64 + hi * 8);
        f16x8 a3 = *(const f16x8*)(hb + ci * 136 + 96 + hi * 8);

        f32x4 z0 = up4(xn0), z1 = up4(xn1), z2 = up4(xn2), z3 = up4(xn3);

        const int tn = (t + 1 < TCH) ? t + 1 : t;
        xn0 = *(const uint2*)(xp + xb0 + (uint)tn * xstep);
        xn1 = *(const uint2*)(xp + xb1 + (uint)tn * xstep);
        xn2 = *(const uint2*)(xp + xb2 + (uint)tn * xstep);
        xn3 = *(const uint2*)(xp + xb3 + (uint)tn * xstep);

        z0 = mfma16(a0, wf00, z0); z0 = mfma16(a1, wf01, z0); z0 = mfma16(a2, wf02, z0); z0 = mfma16(a3, wf03, z0);
        z1 = mfma16(a0, wf10, z1); z1 = mfma16(a1, wf11, z1); z1 = mfma16(a2, wf12, z1); z1 = mfma16(a3, wf13, z1);
        z2 = mfma16(a0, wf20, z2); z2 = mfma16(a1, wf21, z2); z2 = mfma16(a2, wf22, z2); z2 = mfma16(a3, wf23, z2);
        z3 = mfma16(a0, wf30, z3); z3 = mfma16(a1, wf31, z3); z3 = mfma16(a2, wf32, z3); z3 = mfma16(a3, wf33, z3);

        f32x4 hv;
        #pragma unroll
        for (int i = 0; i < 4; ++i) {
            float ig = sigm(z0[i]);
            float fg = sigm(z1[i]);
            float gg = fmaxf(z2[i], 0.0f);
            float og = sigm(z3[i]);
            c[i] = fg * c[i] + ig * gg;
            hv[i] = og * fmaxf(c[i], 0.0f);
        }
        h16 h0 = (h16)hv[0], h1 = (h16)hv[1], h2 = (h16)hv[2], h3 = (h16)hv[3];
        hbuf[(t & 1) ^ 1][r0 + 0][myu] = h0;
        hbuf[(t & 1) ^ 1][r0 + 1][myu] = h1;
        hbuf[(t & 1) ^ 1][r0 + 2][myu] = h2;
        hbuf[(t & 1) ^ 1][r0 + 3][myu] = h3;

        h16x2 p01; p01.x = h0; p01.y = h1;
        h16x2 p23; p23.x = h2; p23.y = h3;
        hp.x = __builtin_bit_cast(uint, p01);
        hp.y = __builtin_bit_cast(uint, p23);
        if (do_hout) *(uint2*)(hout + hob + (uint)t * hstep) = hp;

        __syncthreads();
    }

    *(f32x4*)(cstate + coff) = c;
    *(uint2*)(hstate + ((size_t)bt * KP + myu) * 16 + r0) = hp;
}

__global__ __launch_bounds__(512) void k_rec_single(
    const float* __restrict__ U, const int H,
    const h16* __restrict__ xp, h16* __restrict__ hout, const int do_hout,
    float* __restrict__ cstate, h16* __restrict__ hstate, const int ch)
{
    rec_body(U, H, xp, hout, do_hout, cstate, hstate, ch, blockIdx.x, threadIdx.x);
}

// MID tier: pair only (R14)
__global__ __launch_bounds__(512) void k_rec_pair(
    const float* __restrict__ UA, const int HA, const h16* __restrict__ xpA,
    h16* __restrict__ houtA, const int dohA, float* __restrict__ csA,
    h16* __restrict__ hsA, const int chA,
    const float* __restrict__ UB, const int HB, const h16* __restrict__ xpB,
    h16* __restrict__ houtB, const int dohB, float* __restrict__ csB,
    h16* __restrict__ hsB, const int chB)
{
    const int role = blockIdx.x >> 4;
    const int bt = blockIdx.x & 15;
    rec_body(role ? UB : UA, role ? HB : HA, role ? xpB : xpA,
             role ? houtB : houtA, role ? dohB : dohA,
             role ? csB : csA, role ? hsB : hsA, role ? chB : chA,
             bt, threadIdx.x);
}

// FULL tier: rec1(0) prologue (16 blocks) + dense1(1) rider (256 blocks)
__global__ __launch_bounds__(512) void k_rec1_d1(
    const float* __restrict__ U, const int H,
    const h16* __restrict__ xp, h16* __restrict__ hout,
    float* __restrict__ cstate, h16* __restrict__ hstate,
    const float* __restrict__ x, const float* __restrict__ W1,
    const float* __restrict__ b1, const int ch_d, h16* __restrict__ xp_d)
{
    if (blockIdx.x < 16) {
        rec_body(U, H, xp, hout, 1, cstate, hstate, 0, blockIdx.x, threadIdx.x);
    } else {
        dense_body<0, 4>(x, (const h16*)nullptr, W1, b1, H1_, ch_d, xp_d,
                         blockIdx.x - 16, threadIdx.x);
    }
}

// FULL tier: rec pair (32 blocks) + optional dense1(ch+2) rider (256 blocks)
__global__ __launch_bounds__(512) void k_pair_d1(
    const float* __restrict__ UA, const int HA, const h16* __restrict__ xpA,
    h16* __restrict__ houtA, const int dohA, float* __restrict__ csA,
    h16* __restrict__ hsA, const int chA,
    const float* __restrict__ UB, const int HB, const h16* __restrict__ xpB,
    h16* __restrict__ houtB, const int dohB, float* __restrict__ csB,
    h16* __restrict__ hsB, const int chB,
    const float* __restrict__ x, const float* __restrict__ W1,
    const float* __restrict__ b1, const int ch_d, h16* __restrict__ xp_d,
    const int do_dense)
{
    if (blockIdx.x < 32) {
        const int role = blockIdx.x >> 4;
        const int bt = blockIdx.x & 15;
        rec_body(role ? UB : UA, role ? HB : HA, role ? xpB : xpA,
                 role ? houtB : houtA, role ? dohB : dohA,
                 role ? csB : csA, role ? hsB : hsA, role ? chB : chA,
                 bt, threadIdx.x);
    } else if (do_dense) {
        dense_body<0, 4>(x, (const h16*)nullptr, W1, b1, H1_, ch_d, xp_d,
                         blockIdx.x - 32, threadIdx.x);
    }
}

// ================= head =================
__global__ void k_head(const h16* __restrict__ h2s, const float* __restrict__ Wd,
                       const float* __restrict__ bd, float* __restrict__ out)
{
    __shared__ float lg[OUT_];
    const int b = blockIdx.x, j = threadIdx.x;
    const int bt = b >> 4, r = b & 15;
    if (j < OUT_) {
        float acc = bd[j];
        for (int u = 0; u < H2_; ++u)
            acc += (float)h2s[((size_t)bt * KP + u) * 16 + r] * Wd[u * OUT_ + j];
        lg[j] = acc;
    }
    __syncthreads();
    if (j < OUT_) {
        float m = -1e30f;
        for (int k = 0; k < OUT_; ++k) m = fmaxf(m, lg[k]);
        float s = 0.0f;
        for (int k = 0; k < OUT_; ++k) s += expf(lg[k] - m);
        out[b * OUT_ + j] = expf(lg[j] - m) / s;
    }
}

// ================= R9 fallback (known-good) =================
#define G1_  400
#define G2_  512
#define FBTC 32
#define FB_XP1  0
#define FB_XP2  0
#define FB_WQ   51200
#define FB_XS   134400
#define FB_W2Q  32768
#define FB_H1C  139264
#define FB_U2Q  32768
#define FB_ZBUF 160000
#define FB_H1PK 162048
#define FB_H2PK 162256
#define FB_H2F  162512
#define FB_LDS  163328

__device__ __forceinline__ float fd2(uint wv, uint hv, float cc) {
#if __has_builtin(__builtin_amdgcn_fdot2)
    return __builtin_amdgcn_fdot2(__builtin_bit_cast(h16x2, wv),
                                  __builtin_bit_cast(h16x2, hv), cc, false);
#else
    h16x2 a = __builtin_bit_cast(h16x2, wv), b = __builtin_bit_cast(h16x2, hv);
    return cc + (float)a.x * (float)b.x + (float)a.y * (float)b.y;
#endif
}

__device__ __forceinline__ void stage_quads(const float* __restrict__ P, const int G,
                                            const int NQ, const int KREAL,
                                            char* dst, const int j)
{
    if (j < G) {
        for (int q = 0; q < NQ; ++q) {
            float f[8];
            #pragma unroll
            for (int r = 0; r < 8; ++r) {
                const int k = 8 * q + r;
                f[r] = (k < KREAL) ? P[(size_t)k * G + j] : 0.0f;
            }
            uint4 u;
            u.x = pk2(f[0], f[1]); u.y = pk2(f[2], f[3]);
            u.z = pk2(f[4], f[5]); u.w = pk2(f[6], f[7]);
            *(uint4*)(dst + (size_t)(q * G + j) * 16) = u;
        }
    }
}

__global__ __launch_bounds__(512) void lstm_fallback(
    const float* __restrict__ x,
    const float* __restrict__ W1, const float* __restrict__ U1, const float* __restrict__ b1,
    const float* __restrict__ W2, const float* __restrict__ U2, const float* __restrict__ b2,
    const float* __restrict__ Wd, const float* __restrict__ bd,
    float* __restrict__ out)
{
    __shared__ uint4 smem4[FB_LDS / 16];
    char* sm = (char*)smem4;
    const int b = blockIdx.x;
    const int j = threadIdx.x;
    float c1 = 0.0f, c2 = 0.0f;

    const uint u2r0 = pk2(U2[120 * G2_ + j], U2[121 * G2_ + j]);
    const uint u2r1 = pk2(U2[122 * G2_ + j], U2[123 * G2_ + j]);
    const uint u2r2 = pk2(U2[124 * G2_ + j], U2[125 * G2_ + j]);
    const uint u2r3 = pk2(U2[126 * G2_ + j], U2[127 * G2_ + j]);

    if (j < 52) *(uint*)(sm + FB_H1PK + 4 * j) = 0u;
    if (j < 64) *(uint*)(sm + FB_H2PK + 4 * j) = 0u;
    __syncthreads();

    const float* xrow = x + (size_t)b * T_ * F_;
    for (int ch = 0; ch < T_ / FBTC; ++ch) {
        stage_quads(W1, G1_, 8, 64, sm + FB_WQ, j);
        #pragma unroll
        for (int r = 0; r < 2; ++r) {
            int v = r * 512 + j;
            float2 xv = *(const float2*)(xrow + ch * (FBTC * F_) + 2 * v);
            *(uint*)(sm + FB_XS + 4 * v) = pk2(xv.x, xv.y);
        }
        __syncthreads();
        if (j < G1_) {
            const float bj = b1[j];
            const uint4* WQ = (const uint4*)(sm + FB_WQ);
            for (int t = 0; t < FBTC; ++t) {
                const uint4* XQ = (const uint4*)(sm + FB_XS + t * 128);
                float a0 = bj, a1 = 0.f, a2 = 0.f, a3 = 0.f;
                #pragma unroll
                for (int q = 0; q < 8; ++q) {
                    uint4 wq = WQ[q * G1_ + j]; uint4 hq = XQ[q];
                    a0 = fd2(wq.x, hq.x, a0); a1 = fd2(wq.y, hq.y, a1);
                    a2 = fd2(wq.z, hq.z, a2); a3 = fd2(wq.w, hq.w, a3);
                }
                *(float*)(sm + FB_XP1 + 4 * (t * G1_ + j)) = (a0 + a1) + (a2 + a3);
            }
        }
        __syncthreads();
        stage_quads(U1, G1_, 13, H1_, sm + FB_WQ, j);
        __syncthreads();
        for (int t = 0; t < FBTC; ++t) {
            if (j < G1_) {
                const uint4* WQ = (const uint4*)(sm + FB_WQ);
                const uint4* HP = (const uint4*)(sm + FB_H1PK);
                float a0 = *(const float*)(sm + FB_XP1 + 4 * (t * G1_ + j));
                float a1 = 0.f, a2 = 0.f, a3 = 0.f;
                #pragma unroll
                for (int q = 0; q < 13; ++q) {
                    uint4 wq = WQ[q * G1_ + j]; uint4 hq = HP[q];
                    a0 = fd2(wq.x, hq.x, a0); a1 = fd2(wq.y, hq.y, a1);
                    a2 = fd2(wq.z, hq.z, a2); a3 = fd2(wq.w, hq.w, a3);
                }
                *(float*)(sm + FB_ZBUF + 4 * j) = (a0 + a1) + (a2 + a3);
            }
            __syncthreads();
            if (j < H1_) {
                const float* zb = (const float*)(sm + FB_ZBUF);
                float ig = sigm(zb[j]);
                float fg = sigm(zb[H1_ + j]);
                float gg = fmaxf(zb[2 * H1_ + j], 0.0f);
                float og = sigm(zb[3 * H1_ + j]);
                c1 = fg * c1 + ig * gg;
                float h = og * fmaxf(c1, 0.0f);
                h16 hh = (h16)h;
                *(h16*)(sm + FB_H1PK + 2 * j) = hh;
                *(h16*)(sm + FB_H1C + t * 208 + 2 * j) = hh;
            }
            __syncthreads();
        }
        stage_quads(W2, G2_, 13, H1_, sm + FB_W2Q, j);
        __syncthreads();
        {
            const float bj = b2[j];
            const uint4* WQ = (const uint4*)(sm + FB_W2Q);
            for (int t = 0; t < FBTC; ++t) {
                const uint4* HC = (const uint4*)(sm + FB_H1C + t * 208);
                float a0 = bj, a1 = 0.f, a2 = 0.f, a3 = 0.f;
                #pragma unroll
                for (int q = 0; q < 13; ++q) {
                    uint4 wq = WQ[q * G2_ + j]; uint4 hq = HC[q];
                    a0 = fd2(wq.x, hq.x, a0); a1 = fd2(wq.y, hq.y, a1);
                    a2 = fd2(wq.z, hq.z, a2); a3 = fd2(wq.w, hq.w, a3);
                }
                *(h16*)(sm + FB_XP2 + 2 * (t * G2_ + j)) = (h16)((a0 + a1) + (a2 + a3));
            }
        }
        __syncthreads();
        stage_quads(U2, G2_, 15, 120, sm + FB_U2Q, j);
        __syncthreads();
        for (int t = 0; t < FBTC; ++t) {
            {
                const uint4* WQ = (const uint4*)(sm + FB_U2Q);
                const uint4* HP = (const uint4*)(sm + FB_H2PK);
                float a0 = (float)*(const h16*)(sm + FB_XP2 + 2 * (t * G2_ + j));
                float a1 = 0.f, a2 = 0.f, a3 = 0.f;
                #pragma unroll
                for (int q = 0; q < 15; ++q) {
                    uint4 wq = WQ[q * G2_ + j]; uint4 hq = HP[q];
                    a0 = fd2(wq.x, hq.x, a0); a1 = fd2(wq.y, hq.y, a1);
                    a2 = fd2(wq.z, hq.z, a2); a3 = fd2(wq.w, hq.w, a3);
                }
                uint4 hp15 = ((const uint4*)(sm + FB_H2PK))[15];
                a0 = fd2(u2r0, hp15.x, a0); a1 = fd2(u2r1, hp15.y, a1);
                a2 = fd2(u2r2, hp15.z, a2); a3 = fd2(u2r3, hp15.w, a3);
                *(float*)(sm + FB_ZBUF + 4 * j) = (a0 + a1) + (a2 + a3);
            }
            __syncthreads();
            if (j < H2_) {
                const float* zb = (const float*)(sm + FB_ZBUF);
                float ig = sigm(zb[j]);
                float fg = sigm(zb[H2_ + j]);
                float gg = fmaxf(zb[2 * H2_ + j], 0.0f);
                float og = sigm(zb[3 * H2_ + j]);
                c2 = fg * c2 + ig * gg;
                float h = og * fmaxf(c2, 0.0f);
                *(h16*)(sm + FB_H2PK + 2 * j) = (h16)h;
                *(float*)(sm + FB_H2F + 4 * j) = h;
            }
            __syncthreads();
        }
    }
    if (j < OUT_) {
        const float* h2 = (const float*)(sm + FB_H2F);
        float acc = bd[j];
        #pragma unroll
        for (int k = 0; k < H2_; ++k) acc += h2[k] * Wd[k * OUT_ + j];
        *(float*)(sm + FB_ZBUF + 4 * j) = acc;
    }
    __syncthreads();
    if (j < OUT_) {
        const float* zb = (const float*)(sm + FB_ZBUF);
        float m = -1e30f;
        for (int k = 0; k < OUT_; ++k) m = fmaxf(m, zb[k]);
        float s = 0.0f;
        for (int k = 0; k < OUT_; ++k) s += expf(zb[k] - m);
        out[b * OUT_ + j] = expf(zb[j] - m) / s;
    }
}

// ================= launcher =================
extern "C" void kernel_launch(void* const* d_in, const int* in_sizes, int n_in,
                              void* d_out, int out_size, void* d_ws, size_t ws_size,
                              hipStream_t stream) {
    const float* x  = (const float*)d_in[0];
    const float* W1 = (const float*)d_in[1];
    const float* U1 = (const float*)d_in[2];
    const float* b1 = (const float*)d_in[3];
    const float* W2 = (const float*)d_in[4];
    const float* U2 = (const float*)d_in[5];
    const float* b2 = (const float*)d_in[6];
    const float* Wd = (const float*)d_in[7];
    const float* bd = (const float*)d_in[8];
    float* out = (float*)d_out;

    if (ws_size >= WS_FULL) {
        char* ws = (char*)d_ws;
        h16*   xp1a = (h16*)(ws + F_XP1A);
        h16*   xp1b = (h16*)(ws + F_XP1B);
        h16*   xp2  = (h16*)(ws + F_XP2);
        h16*   h1g  = (h16*)(ws + F_H1G);
        float* c1   = (float*)(ws + F_C1);
        float* c2   = (float*)(ws + F_C2);
        h16*   h1s  = (h16*)(ws + F_H1S);
        h16*   h2s  = (h16*)(ws + F_H2S);
        h16* xp1[2] = { xp1a, xp1b };

        // prologue: dense1(0) -> xp1[0]; then rec1(0) + dense1(1) rider -> xp1[1]
        k_dense<0, 4><<<256, 512, 0, stream>>>(x, (const h16*)nullptr, W1, b1, H1_, 0, xp1[0]);
        k_rec1_d1<<<272, 512, 0, stream>>>(U1, H1_, xp1[0], h1g, c1, h1s,
                                           x, W1, b1, 1, xp1[1]);

        for (int ch = 0; ch < NCH; ++ch) {
            // dense2(ch): consumes h1g(ch)
            k_dense<1, 4><<<256, 512, 0, stream>>>((const float*)nullptr, h1g, W2, b2, H2_, ch, xp2);
            if (ch + 1 < NCH) {
                const int dd = (ch + 2 < NCH) ? 1 : 0;
                // pair: rec2(ch) + rec1(ch+1), with dense1(ch+2) rider on idle CUs
                k_pair_d1<<<288, 512, 0, stream>>>(
                    U2, H2_, xp2, (h16*)nullptr, 0, c2, h2s, ch,
                    U1, H1_, xp1[(ch + 1) & 1], h1g, 1, c1, h1s, ch + 1,
                    x, W1, b1, ch + 2, xp1[ch & 1], dd);
            } else {
                k_rec_single<<<16, 512, 0, stream>>>(U2, H2_, xp2, (h16*)nullptr, 0, c2, h2s, ch);
            }
        }
        k_head<<<256, 64, 0, stream>>>(h2s, Wd, bd, out);
    } else if (ws_size >= WS_MID) {
        char* ws = (char*)d_ws;
        h16*   xp1 = (h16*)(ws + M_XP1);
        h16*   xp2 = (h16*)(ws + M_XP2);
        h16*   h1g = (h16*)(ws + M_H1G);
        float* c1  = (float*)(ws + M_C1);
        float* c2  = (float*)(ws + M_C2);
        h16*   h1s = (h16*)(ws + M_H1S);
        h16*   h2s = (h16*)(ws + M_H2S);

        k_dense<0, 4><<<256, 512, 0, stream>>>(x, (const h16*)nullptr, W1, b1, H1_, 0, xp1);
        k_rec_single<<<16, 512, 0, stream>>>(U1, H1_, xp1, h1g, 1, c1, h1s, 0);

        for (int ch = 0; ch < NCH; ++ch) {
            k_dense<1, 4><<<256, 512, 0, stream>>>((const float*)nullptr, h1g, W2, b2, H2_, ch, xp2);
            if (ch + 1 < NCH) {
                k_dense<0, 4><<<256, 512, 0, stream>>>(x, (const h16*)nullptr, W1, b1, H1_, ch + 1, xp1);
                k_rec_pair<<<32, 512, 0, stream>>>(
                    U2, H2_, xp2, (h16*)nullptr, 0, c2, h2s, ch,
                    U1, H1_, xp1, h1g,           1, c1, h1s, ch + 1);
            } else {
                k_rec_single<<<16, 512, 0, stream>>>(U2, H2_, xp2, (h16*)nullptr, 0, c2, h2s, ch);
            }
        }
        k_head<<<256, 64, 0, stream>>>(h2s, Wd, bd, out);
    } else {
        lstm_fallback<<<B_, 512, 0, stream>>>(x, W1, U1, b1, W2, U2, b2, Wd, bd, out);
    }
}

// Round 16
// 1263.669 us; speedup vs baseline: 1.6745x; 1.0057x over previous
//
#include <hip/hip_runtime.h>
#include <math.h>

// Problem dims
#define B_   256
#define T_   512
#define F_   64
#define H1_  100
#define H2_  128
#define OUT_ 19
#define TCH  64             // timesteps per chunk (pipeline stage)
#define NCH  (T_/TCH)       // 8 chunks
#define NPC  512            // padded+permuted gate columns (both layers)
#define KP   128            // padded K (units) for both layers

typedef unsigned int uint;
typedef _Float16 h16;
typedef __attribute__((ext_vector_type(2))) _Float16 h16x2;
typedef __attribute__((ext_vector_type(8))) _Float16 f16x8;
typedef __attribute__((ext_vector_type(4))) float f32x4;

// ---- workspace layouts (bytes) ----
#define XPW_BYTES (16ull*TCH*NPC*16*2)     // 16,777,216 per xp buffer
#define H1G_BYTES (16ull*TCH*KP*16*2)      // 4,194,304
#define CST_BYTES (16ull*KP*16*4)          // 131,072
#define HST_BYTES (16ull*KP*16*2)          // 65,536

// FULL tier: xp1 double-buffered (dense1 folded into rec dispatches)
#define F_XP1A  0ull
#define F_XP1B  (F_XP1A + XPW_BYTES)
#define F_XP2   (F_XP1B + XPW_BYTES)
#define F_H1G   (F_XP2  + XPW_BYTES)
#define F_C1    (F_H1G  + H1G_BYTES)
#define F_C2    (F_C1   + CST_BYTES)
#define F_H1S   (F_C2   + CST_BYTES)
#define F_H2S   (F_H1S  + HST_BYTES)
#define WS_FULL (F_H2S  + HST_BYTES)       // ~54.9 MB

// MID tier: single xp1
#define M_XP1   0ull
#define M_XP2   (M_XP1 + XPW_BYTES)
#define M_H1G   (M_XP2 + XPW_BYTES)
#define M_C1    (M_H1G + H1G_BYTES)
#define M_C2    (M_C1  + CST_BYTES)
#define M_H1S   (M_C2  + CST_BYTES)
#define M_H2S   (M_H1S + HST_BYTES)
#define WS_MID  (M_H2S + HST_BYTES)        // ~38.1 MB

__device__ __forceinline__ float sigm(float x) { return 1.0f / (1.0f + __expf(-x)); }

__device__ __forceinline__ uint pk2(float a, float b) {
    h16x2 h; h.x = (h16)a; h.y = (h16)b;
    return __builtin_bit_cast(uint, h);
}

__device__ __forceinline__ f32x4 mfma16(f16x8 a, f16x8 b, f32x4 c) {
    return __builtin_amdgcn_mfma_f32_16x16x32_f16(a, b, c, 0, 0, 0);
}

__device__ __forceinline__ f32x4 up4(uint2 v) {
    h16x2 a = __builtin_bit_cast(h16x2, v.x);
    h16x2 b = __builtin_bit_cast(h16x2, v.y);
    f32x4 r; r[0] = (float)a.x; r[1] = (float)a.y; r[2] = (float)b.x; r[3] = (float)b.y;
    return r;
}

// lgkm-only barrier (T4): orders LDS h-exchange across waves WITHOUT draining
// vmcnt, so xp prefetch loads / hout stores stay in flight across steps.
// Hardware-proven correct in R13 (absmax unchanged).
__device__ __forceinline__ void bar_lgkm() {
    asm volatile("s_waitcnt lgkmcnt(0)" ::: "memory");
    __builtin_amdgcn_sched_barrier(0);
    __builtin_amdgcn_s_barrier();
    __builtin_amdgcn_sched_barrier(0);
}

// B-fragment loader with gate-column permutation.
__device__ __forceinline__ f16x8 load_bfrag(const float* __restrict__ P, int H, int OG,
                                            int Kreal, int ubase, int g, int q, int lane) {
    const int u  = ubase + (lane & 15);
    const int k0 = q * 32 + (lane >> 4) * 8;
    const int col = g * H + u;
    float f[8];
    #pragma unroll
    for (int e = 0; e < 8; ++e) {
        const int k = k0 + e;
        f[e] = (u < H && k < Kreal) ? P[(size_t)k * OG + col] : 0.0f;
    }
    uint4 r;
    r.x = pk2(f[0], f[1]); r.y = pk2(f[2], f[3]);
    r.z = pk2(f[4], f[5]); r.w = pk2(f[6], f[7]);
    return __builtin_bit_cast(f16x8, r);
}

// ================= dense pre-projection body =================
template<int MODE, int NIT>
__device__ __forceinline__ void dense_body(
    const float* __restrict__ Af, const h16* __restrict__ Ah,
    const float* __restrict__ W, const float* __restrict__ bias,
    const int H, const int ch, h16* __restrict__ xp,
    const int bid, const int j)
{
    const int lane = j & 63, w = j >> 6;
    const int KF = MODE ? 4 : 2;
    const int KREAL = MODE ? 100 : 64;
    const int OG = 4 * H;

    f16x8 bf[4][4];
    #pragma unroll
    for (int g = 0; g < 4; ++g)
        #pragma unroll
        for (int q = 0; q < 4; ++q)
            if (q < KF) bf[g][q] = load_bfrag(W, H, OG, KREAL, w * 16, g, q, lane);

    float bv[4];
    #pragma unroll
    for (int g = 0; g < 4; ++g) {
        const int u = w * 16 + (lane & 15);
        bv[g] = (u < H) ? bias[g * H + u] : 0.0f;
    }

    const int ci = lane & 15, hi = lane >> 4;
    #pragma unroll
    for (int it = 0; it < NIT; ++it) {
        const int m = bid * NIT + it;
        const int bt = m / TCH, tc = m % TCH;

        f16x8 af[4];
        if (MODE == 0) {
            const int b = bt * 16 + ci;
            const int t = ch * TCH + tc;
            #pragma unroll
            for (int q = 0; q < 2; ++q) {
                const int k0 = q * 32 + hi * 8;
                const float* p = Af + ((size_t)b * T_ + t) * F_ + k0;
                float4 x0 = *(const float4*)p;
                float4 x1 = *(const float4*)(p + 4);
                uint4 r;
                r.x = pk2(x0.x, x0.y); r.y = pk2(x0.z, x0.w);
                r.z = pk2(x1.x, x1.y); r.w = pk2(x1.z, x1.w);
                af[q] = __builtin_bit_cast(f16x8, r);
            }
        } else {
            #pragma unroll
            for (int q = 0; q < 4; ++q) {
                const int k0 = q * 32 + hi * 8;
                const size_t base = ((size_t)(bt * TCH + tc) * KP + k0) * 16 + ci;
                f16x8 a;
                #pragma unroll
                for (int e = 0; e < 8; ++e) a[e] = Ah[base + (size_t)e * 16];
                af[q] = a;
            }
        }

        f32x4 acc[4];
        #pragma unroll
        for (int g = 0; g < 4; ++g) { acc[g][0]=bv[g]; acc[g][1]=bv[g]; acc[g][2]=bv[g]; acc[g][3]=bv[g]; }
        #pragma unroll
        for (int g = 0; g < 4; ++g)
            #pragma unroll
            for (int q = 0; q < 4; ++q)
                if (q < KF) acc[g] = mfma16(af[q], bf[g][q], acc[g]);

        #pragma unroll
        for (int g = 0; g < 4; ++g) {
            const int c = (w * 4 + g) * 16 + ci;
            const size_t o = ((size_t)(bt * TCH + tc) * NPC + c) * 16 + hi * 4;
            uint2 s;
            s.x = pk2(acc[g][0], acc[g][1]);
            s.y = pk2(acc[g][2], acc[g][3]);
            *(uint2*)(xp + o) = s;
        }
    }
}

template<int MODE, int NIT>
__global__ __launch_bounds__(512) void k_dense(
    const float* __restrict__ Af, const h16* __restrict__ Ah,
    const float* __restrict__ W, const float* __restrict__ bias,
    const int H, const int ch, h16* __restrict__ xp)
{
    dense_body<MODE, NIT>(Af, Ah, W, bias, H, ch, xp, blockIdx.x, threadIdx.x);
}

// ================= recurrence body =================
// R11 structure + bar_lgkm per step (no vmcnt drain) + prefetch-depth-2 ring.
#define LF(G,Q) f16x8 wf##G##Q = load_bfrag(U, H, 4*H, H, w * 16, G, Q, lane); \
                asm volatile("" ::: "memory");

// One recurrence step consuming prefetch buffer Pn (4 named uint2 regs),
// then refilling Pn with step t+2's xp (2 steps of latency slack).
#define RSTEP(Pn, tcur)                                                          \
    {                                                                            \
        const int t_ = (tcur);                                                   \
        const h16* hb = &hbuf[t_ & 1][0][0];                                     \
        f16x8 a0 = *(const f16x8*)(hb + ci * 136 + 0  + hi * 8);                 \
        f16x8 a1 = *(const f16x8*)(hb + ci * 136 + 32 + hi * 8);                 \
        f16x8 a2 = *(const f16x8*)(hb + ci * 136 + 64 + hi * 8);                 \
        f16x8 a3 = *(const f16x8*)(hb + ci * 136 + 96 + hi * 8);                 \
        f32x4 z0 = up4(Pn##0), z1 = up4(Pn##1), z2 = up4(Pn##2), z3 = up4(Pn##3);\
        const uint to_ = (uint)((t_ + 2 < TCH) ? t_ + 2 : t_) * xstep;           \
        Pn##0 = *(const uint2*)(xp + xb0 + to_);                                 \
        Pn##1 = *(const uint2*)(xp + xb1 + to_);                                 \
        Pn##2 = *(const uint2*)(xp + xb2 + to_);                                 \
        Pn##3 = *(const uint2*)(xp + xb3 + to_);                                 \
        z0 = mfma16(a0, wf00, z0); z0 = mfma16(a1, wf01, z0);                    \
        z0 = mfma16(a2, wf02, z0); z0 = mfma16(a3, wf03, z0);                    \
        z1 = mfma16(a0, wf10, z1); z1 = mfma16(a1, wf11, z1);                    \
        z1 = mfma16(a2, wf12, z1); z1 = mfma16(a3, wf13, z1);                    \
        z2 = mfma16(a0, wf20, z2); z2 = mfma16(a1, wf21, z2);                    \
        z2 = mfma16(a2, wf22, z2); z2 = mfma16(a3, wf23, z2);                    \
        z3 = mfma16(a0, wf30, z3); z3 = mfma16(a1, wf31, z3);                    \
        z3 = mfma16(a2, wf32, z3); z3 = mfma16(a3, wf33, z3);                    \
        f32x4 hv;                                                                \
        _Pragma("unroll")                                                        \
        for (int i = 0; i < 4; ++i) {                                            \
            float ig = sigm(z0[i]);                                              \
            float fg = sigm(z1[i]);                                              \
            float gg = fmaxf(z2[i], 0.0f);                                       \
            float og = sigm(z3[i]);                                              \
            c[i] = fg * c[i] + ig * gg;                                          \
            hv[i] = og * fmaxf(c[i], 0.0f);                                      \
        }                                                                        \
        h16 h0 = (h16)hv[0], h1 = (h16)hv[1], h2 = (h16)hv[2], h3 = (h16)hv[3]; \
        const int nb_ = (t_ & 1) ^ 1;                                            \
        hbuf[nb_][r0 + 0][myu] = h0;                                             \
        hbuf[nb_][r0 + 1][myu] = h1;                                             \
        hbuf[nb_][r0 + 2][myu] = h2;                                             \
        hbuf[nb_][r0 + 3][myu] = h3;                                             \
        h16x2 p01_; p01_.x = h0; p01_.y = h1;                                    \
        h16x2 p23_; p23_.x = h2; p23_.y = h3;                                    \
        hp.x = __builtin_bit_cast(uint, p01_);                                   \
        hp.y = __builtin_bit_cast(uint, p23_);                                   \
        if (do_hout) *(uint2*)(hout + hob + (uint)t_ * hstep) = hp;              \
        bar_lgkm();                                                              \
    }

__device__ __forceinline__ void rec_body(
    const float* __restrict__ U, const int H,
    const h16* __restrict__ xp, h16* __restrict__ hout, const int do_hout,
    float* __restrict__ cstate, h16* __restrict__ hstate, const int ch,
    const int bt, const int j)
{
    __shared__ h16 hbuf[2][16][136];
    const int lane = j & 63, w = j >> 6;
    const int ci = lane & 15, hi = lane >> 4;
    const int myu = w * 16 + ci;
    const int r0 = hi * 4;

    LF(0,0) LF(0,1) LF(0,2) LF(0,3)
    LF(1,0) LF(1,1) LF(1,2) LF(1,3)
    LF(2,0) LF(2,1) LF(2,2) LF(2,3)
    LF(3,0) LF(3,1) LF(3,2) LF(3,3)

    {
        const int u = j & 127, rr = (j >> 7) * 4;
        #pragma unroll
        for (int i = 0; i < 4; ++i) {
            h16 v = (h16)0.0f;
            if (ch != 0) v = hstate[((size_t)bt * KP + u) * 16 + rr + i];
            hbuf[0][rr + i][u] = v;
        }
    }
    f32x4 c;
    const size_t coff = ((size_t)bt * KP + myu) * 16 + r0;
    if (ch == 0) { c[0]=0.f; c[1]=0.f; c[2]=0.f; c[3]=0.f; }
    else         { c = *(const f32x4*)(cstate + coff); }
    __syncthreads();

    const uint xstep = NPC * 16;
    const uint xb0 = (uint)(((size_t)bt * TCH) * NPC + (w * 64 + ci)) * 16 + r0;
    const uint xb1 = xb0 + 16 * 16, xb2 = xb0 + 32 * 16, xb3 = xb0 + 48 * 16;

    // prefetch ring depth 2: pA holds step tt, pB holds step tt+1
    uint2 pA0 = *(const uint2*)(xp + xb0);
    uint2 pA1 = *(const uint2*)(xp + xb1);
    uint2 pA2 = *(const uint2*)(xp + xb2);
    uint2 pA3 = *(const uint2*)(xp + xb3);
    uint2 pB0 = *(const uint2*)(xp + xb0 + xstep);
    uint2 pB1 = *(const uint2*)(xp + xb1 + xstep);
    uint2 pB2 = *(const uint2*)(xp + xb2 + xstep);
    uint2 pB3 = *(const uint2*)(xp + xb3 + xstep);

    const uint hstep = KP * 16;
    const uint hob = (uint)(((size_t)bt * TCH) * KP + myu) * 16 + r0;

    uint2 hp; hp.x = 0u; hp.y = 0u;

    for (int tt = 0; tt < TCH; tt += 2) {
        RSTEP(pA, tt)
        RSTEP(pB, tt + 1)
    }

    *(f32x4*)(cstate + coff) = c;
    *(uint2*)(hstate + ((size_t)bt * KP + myu) * 16 + r0) = hp;
}

__global__ __launch_bounds__(512) void k_rec_single(
    const float* __restrict__ U, const int H,
    const h16* __restrict__ xp, h16* __restrict__ hout, const int do_hout,
    float* __restrict__ cstate, h16* __restrict__ hstate, const int ch)
{
    rec_body(U, H, xp, hout, do_hout, cstate, hstate, ch, blockIdx.x, threadIdx.x);
}

// MID tier: pair only
__global__ __launch_bounds__(512) void k_rec_pair(
    const float* __restrict__ UA, const int HA, const h16* __restrict__ xpA,
    h16* __restrict__ houtA, const int dohA, float* __restrict__ csA,
    h16* __restrict__ hsA, const int chA,
    const float* __restrict__ UB, const int HB, const h16* __restrict__ xpB,
    h16* __restrict__ houtB, const int dohB, float* __restrict__ csB,
    h16* __restrict__ hsB, const int chB)
{
    const int role = blockIdx.x >> 4;
    const int bt = blockIdx.x & 15;
    rec_body(role ? UB : UA, role ? HB : HA, role ? xpB : xpA,
             role ? houtB : houtA, role ? dohB : dohA,
             role ? csB : csA, role ? hsB : hsA, role ? chB : chA,
             bt, threadIdx.x);
}

// FULL tier: rec1(0) prologue (16 blocks) + dense1(1) rider (256 blocks)
__global__ __launch_bounds__(512) void k_rec1_d1(
    const float* __restrict__ U, const int H,
    const h16* __restrict__ xp, h16* __restrict__ hout,
    float* __restrict__ cstate, h16* __restrict__ hstate,
    const float* __restrict__ x, const float* __restrict__ W1,
    const float* __restrict__ b1, const int ch_d, h16* __restrict__ xp_d)
{
    if (blockIdx.x < 16) {
        rec_body(U, H, xp, hout, 1, cstate, hstate, 0, blockIdx.x, threadIdx.x);
    } else {
        dense_body<0, 4>(x, (const h16*)nullptr, W1, b1, H1_, ch_d, xp_d,
                         blockIdx.x - 16, threadIdx.x);
    }
}

// FULL tier: rec pair (32 blocks) + optional dense1(ch+2) rider (256 blocks)
__global__ __launch_bounds__(512) void k_pair_d1(
    const float* __restrict__ UA, const int HA, const h16* __restrict__ xpA,
    h16* __restrict__ houtA, const int dohA, float* __restrict__ csA,
    h16* __restrict__ hsA, const int chA,
    const float* __restrict__ UB, const int HB, const h16* __restrict__ xpB,
    h16* __restrict__ houtB, const int dohB, float* __restrict__ csB,
    h16* __restrict__ hsB, const int chB,
    const float* __restrict__ x, const float* __restrict__ W1,
    const float* __restrict__ b1, const int ch_d, h16* __restrict__ xp_d,
    const int do_dense)
{
    if (blockIdx.x < 32) {
        const int role = blockIdx.x >> 4;
        const int bt = blockIdx.x & 15;
        rec_body(role ? UB : UA, role ? HB : HA, role ? xpB : xpA,
                 role ? houtB : houtA, role ? dohB : dohA,
                 role ? csB : csA, role ? hsB : hsA, role ? chB : chA,
                 bt, threadIdx.x);
    } else if (do_dense) {
        dense_body<0, 4>(x, (const h16*)nullptr, W1, b1, H1_, ch_d, xp_d,
                         blockIdx.x - 32, threadIdx.x);
    }
}

// ================= head =================
__global__ void k_head(const h16* __restrict__ h2s, const float* __restrict__ Wd,
                       const float* __restrict__ bd, float* __restrict__ out)
{
    __shared__ float lg[OUT_];
    const int b = blockIdx.x, j = threadIdx.x;
    const int bt = b >> 4, r = b & 15;
    if (j < OUT_) {
        float acc = bd[j];
        for (int u = 0; u < H2_; ++u)
            acc += (float)h2s[((size_t)bt * KP + u) * 16 + r] * Wd[u * OUT_ + j];
        lg[j] = acc;
    }
    __syncthreads();
    if (j < OUT_) {
        float m = -1e30f;
        for (int k = 0; k < OUT_; ++k) m = fmaxf(m, lg[k]);
        float s = 0.0f;
        for (int k = 0; k < OUT_; ++k) s += expf(lg[k] - m);
        out[b * OUT_ + j] = expf(lg[j] - m) / s;
    }
}

// ================= R9 fallback (known-good) =================
#define G1_  400
#define G2_  512
#define FBTC 32
#define FB_XP1  0
#define FB_XP2  0
#define FB_WQ   51200
#define FB_XS   134400
#define FB_W2Q  32768
#define FB_H1C  139264
#define FB_U2Q  32768
#define FB_ZBUF 160000
#define FB_H1PK 162048
#define FB_H2PK 162256
#define FB_H2F  162512
#define FB_LDS  163328

__device__ __forceinline__ float fd2(uint wv, uint hv, float cc) {
#if __has_builtin(__builtin_amdgcn_fdot2)
    return __builtin_amdgcn_fdot2(__builtin_bit_cast(h16x2, wv),
                                  __builtin_bit_cast(h16x2, hv), cc, false);
#else
    h16x2 a = __builtin_bit_cast(h16x2, wv), b = __builtin_bit_cast(h16x2, hv);
    return cc + (float)a.x * (float)b.x + (float)a.y * (float)b.y;
#endif
}

__device__ __forceinline__ void stage_quads(const float* __restrict__ P, const int G,
                                            const int NQ, const int KREAL,
                                            char* dst, const int j)
{
    if (j < G) {
        for (int q = 0; q < NQ; ++q) {
            float f[8];
            #pragma unroll
            for (int r = 0; r < 8; ++r) {
                const int k = 8 * q + r;
                f[r] = (k < KREAL) ? P[(size_t)k * G + j] : 0.0f;
            }
            uint4 u;
            u.x = pk2(f[0], f[1]); u.y = pk2(f[2], f[3]);
            u.z = pk2(f[4], f[5]); u.w = pk2(f[6], f[7]);
            *(uint4*)(dst + (size_t)(q * G + j) * 16) = u;
        }
    }
}

__global__ __launch_bounds__(512) void lstm_fallback(
    const float* __restrict__ x,
    const float* __restrict__ W1, const float* __restrict__ U1, const float* __restrict__ b1,
    const float* __restrict__ W2, const float* __restrict__ U2, const float* __restrict__ b2,
    const float* __restrict__ Wd, const float* __restrict__ bd,
    float* __restrict__ out)
{
    __shared__ uint4 smem4[FB_LDS / 16];
    char* sm = (char*)smem4;
    const int b = blockIdx.x;
    const int j = threadIdx.x;
    float c1 = 0.0f, c2 = 0.0f;

    const uint u2r0 = pk2(U2[120 * G2_ + j], U2[121 * G2_ + j]);
    const uint u2r1 = pk2(U2[122 * G2_ + j], U2[123 * G2_ + j]);
    const uint u2r2 = pk2(U2[124 * G2_ + j], U2[125 * G2_ + j]);
    const uint u2r3 = pk2(U2[126 * G2_ + j], U2[127 * G2_ + j]);

    if (j < 52) *(uint*)(sm + FB_H1PK + 4 * j) = 0u;
    if (j < 64) *(uint*)(sm + FB_H2PK + 4 * j) = 0u;
    __syncthreads();

    const float* xrow = x + (size_t)b * T_ * F_;
    for (int ch = 0; ch < T_ / FBTC; ++ch) {
        stage_quads(W1, G1_, 8, 64, sm + FB_WQ, j);
        #pragma unroll
        for (int r = 0; r < 2; ++r) {
            int v = r * 512 + j;
            float2 xv = *(const float2*)(xrow + ch * (FBTC * F_) + 2 * v);
            *(uint*)(sm + FB_XS + 4 * v) = pk2(xv.x, xv.y);
        }
        __syncthreads();
        if (j < G1_) {
            const float bj = b1[j];
            const uint4* WQ = (const uint4*)(sm + FB_WQ);
            for (int t = 0; t < FBTC; ++t) {
                const uint4* XQ = (const uint4*)(sm + FB_XS + t * 128);
                float a0 = bj, a1 = 0.f, a2 = 0.f, a3 = 0.f;
                #pragma unroll
                for (int q = 0; q < 8; ++q) {
                    uint4 wq = WQ[q * G1_ + j]; uint4 hq = XQ[q];
                    a0 = fd2(wq.x, hq.x, a0); a1 = fd2(wq.y, hq.y, a1);
                    a2 = fd2(wq.z, hq.z, a2); a3 = fd2(wq.w, hq.w, a3);
                }
                *(float*)(sm + FB_XP1 + 4 * (t * G1_ + j)) = (a0 + a1) + (a2 + a3);
            }
        }
        __syncthreads();
        stage_quads(U1, G1_, 13, H1_, sm + FB_WQ, j);
        __syncthreads();
        for (int t = 0; t < FBTC; ++t) {
            if (j < G1_) {
                const uint4* WQ = (const uint4*)(sm + FB_WQ);
                const uint4* HP = (const uint4*)(sm + FB_H1PK);
                float a0 = *(const float*)(sm + FB_XP1 + 4 * (t * G1_ + j));
                float a1 = 0.f, a2 = 0.f, a3 = 0.f;
                #pragma unroll
                for (int q = 0; q < 13; ++q) {
                    uint4 wq = WQ[q * G1_ + j]; uint4 hq = HP[q];
                    a0 = fd2(wq.x, hq.x, a0); a1 = fd2(wq.y, hq.y, a1);
                    a2 = fd2(wq.z, hq.z, a2); a3 = fd2(wq.w, hq.w, a3);
                }
                *(float*)(sm + FB_ZBUF + 4 * j) = (a0 + a1) + (a2 + a3);
            }
            __syncthreads();
            if (j < H1_) {
                const float* zb = (const float*)(sm + FB_ZBUF);
                float ig = sigm(zb[j]);
                float fg = sigm(zb[H1_ + j]);
                float gg = fmaxf(zb[2 * H1_ + j], 0.0f);
                float og = sigm(zb[3 * H1_ + j]);
                c1 = fg * c1 + ig * gg;
                float h = og * fmaxf(c1, 0.0f);
                h16 hh = (h16)h;
                *(h16*)(sm + FB_H1PK + 2 * j) = hh;
                *(h16*)(sm + FB_H1C + t * 208 + 2 * j) = hh;
            }
            __syncthreads();
        }
        stage_quads(W2, G2_, 13, H1_, sm + FB_W2Q, j);
        __syncthreads();
        {
            const float bj = b2[j];
            const uint4* WQ = (const uint4*)(sm + FB_W2Q);
            for (int t = 0; t < FBTC; ++t) {
                const uint4* HC = (const uint4*)(sm + FB_H1C + t * 208);
                float a0 = bj, a1 = 0.f, a2 = 0.f, a3 = 0.f;
                #pragma unroll
                for (int q = 0; q < 13; ++q) {
                    uint4 wq = WQ[q * G2_ + j]; uint4 hq = HC[q];
                    a0 = fd2(wq.x, hq.x, a0); a1 = fd2(wq.y, hq.y, a1);
                    a2 = fd2(wq.z, hq.z, a2); a3 = fd2(wq.w, hq.w, a3);
                }
                *(h16*)(sm + FB_XP2 + 2 * (t * G2_ + j)) = (h16)((a0 + a1) + (a2 + a3));
            }
        }
        __syncthreads();
        stage_quads(U2, G2_, 15, 120, sm + FB_U2Q, j);
        __syncthreads();
        for (int t = 0; t < FBTC; ++t) {
            {
                const uint4* WQ = (const uint4*)(sm + FB_U2Q);
                const uint4* HP = (const uint4*)(sm + FB_H2PK);
                float a0 = (float)*(const h16*)(sm + FB_XP2 + 2 * (t * G2_ + j));
                float a1 = 0.f, a2 = 0.f, a3 = 0.f;
                #pragma unroll
                for (int q = 0; q < 15; ++q) {
                    uint4 wq = WQ[q * G2_ + j]; uint4 hq = HP[q];
                    a0 = fd2(wq.x, hq.x, a0); a1 = fd2(wq.y, hq.y, a1);
                    a2 = fd2(wq.z, hq.z, a2); a3 = fd2(wq.w, hq.w, a3);
                }
                uint4 hp15 = ((const uint4*)(sm + FB_H2PK))[15];
                a0 = fd2(u2r0, hp15.x, a0); a1 = fd2(u2r1, hp15.y, a1);
                a2 = fd2(u2r2, hp15.z, a2); a3 = fd2(u2r3, hp15.w, a3);
                *(float*)(sm + FB_ZBUF + 4 * j) = (a0 + a1) + (a2 + a3);
            }
            __syncthreads();
            if (j < H2_) {
                const float* zb = (const float*)(sm + FB_ZBUF);
                float ig = sigm(zb[j]);
                float fg = sigm(zb[H2_ + j]);
                float gg = fmaxf(zb[2 * H2_ + j], 0.0f);
                float og = sigm(zb[3 * H2_ + j]);
                c2 = fg * c2 + ig * gg;
                float h = og * fmaxf(c2, 0.0f);
                *(h16*)(sm + FB_H2PK + 2 * j) = (h16)h;
                *(float*)(sm + FB_H2F + 4 * j) = h;
            }
            __syncthreads();
        }
    }
    if (j < OUT_) {
        const float* h2 = (const float*)(sm + FB_H2F);
        float acc = bd[j];
        #pragma unroll
        for (int k = 0; k < H2_; ++k) acc += h2[k] * Wd[k * OUT_ + j];
        *(float*)(sm + FB_ZBUF + 4 * j) = acc;
    }
    __syncthreads();
    if (j < OUT_) {
        const float* zb = (const float*)(sm + FB_ZBUF);
        float m = -1e30f;
        for (int k = 0; k < OUT_; ++k) m = fmaxf(m, zb[k]);
        float s = 0.0f;
        for (int k = 0; k < OUT_; ++k) s += expf(zb[k] - m);
        out[b * OUT_ + j] = expf(zb[j] - m) / s;
    }
}

// ================= launcher =================
extern "C" void kernel_launch(void* const* d_in, const int* in_sizes, int n_in,
                              void* d_out, int out_size, void* d_ws, size_t ws_size,
                              hipStream_t stream) {
    const float* x  = (const float*)d_in[0];
    const float* W1 = (const float*)d_in[1];
    const float* U1 = (const float*)d_in[2];
    const float* b1 = (const float*)d_in[3];
    const float* W2 = (const float*)d_in[4];
    const float* U2 = (const float*)d_in[5];
    const float* b2 = (const float*)d_in[6];
    const float* Wd = (const float*)d_in[7];
    const float* bd = (const float*)d_in[8];
    float* out = (float*)d_out;

    if (ws_size >= WS_FULL) {
        char* ws = (char*)d_ws;
        h16*   xp1a = (h16*)(ws + F_XP1A);
        h16*   xp1b = (h16*)(ws + F_XP1B);
        h16*   xp2  = (h16*)(ws + F_XP2);
        h16*   h1g  = (h16*)(ws + F_H1G);
        float* c1   = (float*)(ws + F_C1);
        float* c2   = (float*)(ws + F_C2);
        h16*   h1s  = (h16*)(ws + F_H1S);
        h16*   h2s  = (h16*)(ws + F_H2S);
        h16* xp1[2] = { xp1a, xp1b };

        k_dense<0, 4><<<256, 512, 0, stream>>>(x, (const h16*)nullptr, W1, b1, H1_, 0, xp1[0]);
        k_rec1_d1<<<272, 512, 0, stream>>>(U1, H1_, xp1[0], h1g, c1, h1s,
                                           x, W1, b1, 1, xp1[1]);

        for (int ch = 0; ch < NCH; ++ch) {
            k_dense<1, 4><<<256, 512, 0, stream>>>((const float*)nullptr, h1g, W2, b2, H2_, ch, xp2);
            if (ch + 1 < NCH) {
                const int dd = (ch + 2 < NCH) ? 1 : 0;
                k_pair_d1<<<288, 512, 0, stream>>>(
                    U2, H2_, xp2, (h16*)nullptr, 0, c2, h2s, ch,
                    U1, H1_, xp1[(ch + 1) & 1], h1g, 1, c1, h1s, ch + 1,
                    x, W1, b1, ch + 2, xp1[ch & 1], dd);
            } else {
                k_rec_single<<<16, 512, 0, stream>>>(U2, H2_, xp2, (h16*)nullptr, 0, c2, h2s, ch);
            }
        }
        k_head<<<256, 64, 0, stream>>>(h2s, Wd, bd, out);
    } else if (ws_size >= WS_MID) {
        char* ws = (char*)d_ws;
        h16*   xp1 = (h16*)(ws + M_XP1);
        h16*   xp2 = (h16*)(ws + M_XP2);
        h16*   h1g = (h16*)(ws + M_H1G);
        float* c1  = (float*)(ws + M_C1);
        float* c2  = (float*)(ws + M_C2);
        h16*   h1s = (h16*)(ws + M_H1S);
        h16*   h2s = (h16*)(ws + M_H2S);

        k_dense<0, 4><<<256, 512, 0, stream>>>(x, (const h16*)nullptr, W1, b1, H1_, 0, xp1);
        k_rec_single<<<16, 512, 0, stream>>>(U1, H1_, xp1, h1g, 1, c1, h1s, 0);

        for (int ch = 0; ch < NCH; ++ch) {
            k_dense<1, 4><<<256, 512, 0, stream>>>((const float*)nullptr, h1g, W2, b2, H2_, ch, xp2);
            if (ch + 1 < NCH) {
                k_dense<0, 4><<<256, 512, 0, stream>>>(x, (const h16*)nullptr, W1, b1, H1_, ch + 1, xp1);
                k_rec_pair<<<32, 512, 0, stream>>>(
                    U2, H2_, xp2, (h16*)nullptr, 0, c2, h2s, ch,
                    U1, H1_, xp1, h1g,           1, c1, h1s, ch + 1);
            } else {
                k_rec_single<<<16, 512, 0, stream>>>(U2, H2_, xp2, (h16*)nullptr, 0, c2, h2s, ch);
            }
        }
        k_head<<<256, 64, 0, stream>>>(h2s, Wd, bd, out);
    } else {
        lstm_fallback<<<B_, 512, 0, stream>>>(x, W1, U1, b1, W2, U2, b2, Wd, bd, out);
    }
}

// Round 17
// 972.516 us; speedup vs baseline: 2.1758x; 1.2994x over previous
//
#include <hip/hip_runtime.h>
#include <math.h>

// Problem dims
#define B_   256
#define T_   512
#define F_   64
#define H1_  100
#define H2_  128
#define OUT_ 19
#define TCH  64             // timesteps per chunk (pipeline stage)
#define NCH  (T_/TCH)       // 8 chunks
#define NPC  512            // padded+permuted gate columns (both layers)
#define KP   128            // padded K (units) for both layers

typedef unsigned int uint;
typedef _Float16 h16;
typedef __attribute__((ext_vector_type(2))) _Float16 h16x2;
typedef __attribute__((ext_vector_type(8))) _Float16 f16x8;
typedef __attribute__((ext_vector_type(4))) float f32x4;

// ---- workspace layouts (bytes) ----
#define XPW_BYTES (16ull*TCH*NPC*16*2)     // 16,777,216 per xp buffer
#define H1G_BYTES (16ull*TCH*KP*16*2)      // 4,194,304
#define CST_BYTES (16ull*KP*16*4)          // 131,072
#define HST_BYTES (16ull*KP*16*2)          // 65,536
#define UF_BYTES  (128ull*64*8*2)          // 131,072 per packed-U buffer

// FULL tier: xp1 double-buffered (dense1 folded into rec dispatches)
#define F_XP1A  0ull
#define F_XP1B  (F_XP1A + XPW_BYTES)
#define F_XP2   (F_XP1B + XPW_BYTES)
#define F_H1G   (F_XP2  + XPW_BYTES)
#define F_C1    (F_H1G  + H1G_BYTES)
#define F_C2    (F_C1   + CST_BYTES)
#define F_H1S   (F_C2   + CST_BYTES)
#define F_H2S   (F_H1S  + HST_BYTES)
#define F_U1F   (F_H2S  + HST_BYTES)
#define F_U2F   (F_U1F  + UF_BYTES)
#define WS_FULL (F_U2F  + UF_BYTES)        // ~55.2 MB

// MID tier: single xp1
#define M_XP1   0ull
#define M_XP2   (M_XP1 + XPW_BYTES)
#define M_H1G   (M_XP2 + XPW_BYTES)
#define M_C1    (M_H1G + H1G_BYTES)
#define M_C2    (M_C1  + CST_BYTES)
#define M_H1S   (M_C2  + CST_BYTES)
#define M_H2S   (M_H1S + HST_BYTES)
#define M_U1F   (M_H2S + HST_BYTES)
#define M_U2F   (M_U1F + UF_BYTES)
#define WS_MID  (M_U2F + UF_BYTES)         // ~38.4 MB

__device__ __forceinline__ float sigm(float x) { return 1.0f / (1.0f + __expf(-x)); }

__device__ __forceinline__ uint pk2(float a, float b) {
    h16x2 h; h.x = (h16)a; h.y = (h16)b;
    return __builtin_bit_cast(uint, h);
}

__device__ __forceinline__ f32x4 mfma16(f16x8 a, f16x8 b, f32x4 c) {
    return __builtin_amdgcn_mfma_f32_16x16x32_f16(a, b, c, 0, 0, 0);
}

__device__ __forceinline__ f32x4 up4(uint2 v) {
    h16x2 a = __builtin_bit_cast(h16x2, v.x);
    h16x2 b = __builtin_bit_cast(h16x2, v.y);
    f32x4 r; r[0] = (float)a.x; r[1] = (float)a.y; r[2] = (float)b.x; r[3] = (float)b.y;
    return r;
}

// lgkm-only barrier (T4): orders LDS h-exchange without draining vmcnt.
__device__ __forceinline__ void bar_lgkm() {
    asm volatile("s_waitcnt lgkmcnt(0)" ::: "memory");
    __builtin_amdgcn_sched_barrier(0);
    __builtin_amdgcn_s_barrier();
    __builtin_amdgcn_sched_barrier(0);
}

// B-fragment loader with gate-column permutation (strided; used by dense + prepack).
__device__ __forceinline__ f16x8 load_bfrag(const float* __restrict__ P, int H, int OG,
                                            int Kreal, int ubase, int g, int q, int lane) {
    const int u  = ubase + (lane & 15);
    const int k0 = q * 32 + (lane >> 4) * 8;
    const int col = g * H + u;
    float f[8];
    #pragma unroll
    for (int e = 0; e < 8; ++e) {
        const int k = k0 + e;
        f[e] = (u < H && k < Kreal) ? P[(size_t)k * OG + col] : 0.0f;
    }
    uint4 r;
    r.x = pk2(f[0], f[1]); r.y = pk2(f[2], f[3]);
    r.z = pk2(f[4], f[5]); r.w = pk2(f[6], f[7]);
    return __builtin_bit_cast(f16x8, r);
}

// ================= weight prepack (runs once) =================
// Packs U1/U2 into per-lane MFMA fragment layout so rec prologues become
// 16 coalesced 16B/lane loads instead of 128 strided scalar loads.
// Fragment (w,g,q) of lane l lives at Uf[(((w*4+g)*4+q)*64 + l)*8 .. +8).
__global__ __launch_bounds__(512) void k_prepack(
    const float* __restrict__ U1, const float* __restrict__ U2,
    h16* __restrict__ U1f, h16* __restrict__ U2f)
{
    const int w = blockIdx.x & 7;
    const int layer = blockIdx.x >> 3;
    const float* U = layer ? U2 : U1;
    const int H = layer ? H2_ : H1_;
    h16* Uf = layer ? U2f : U1f;
    const int lane = threadIdx.x & 63;
    #pragma unroll
    for (int it = 0; it < 2; ++it) {
        const int combo = it * 8 + (threadIdx.x >> 6);
        const int g = combo >> 2, q = combo & 3;
        f16x8 fr = load_bfrag(U, H, 4 * H, H, w * 16, g, q, lane);
        *(f16x8*)(Uf + (size_t)(((w * 4 + g) * 4 + q) * 64 + lane) * 8) = fr;
    }
}

// ================= dense pre-projection body =================
template<int MODE, int NIT>
__device__ __forceinline__ void dense_body(
    const float* __restrict__ Af, const h16* __restrict__ Ah,
    const float* __restrict__ W, const float* __restrict__ bias,
    const int H, const int ch, h16* __restrict__ xp,
    const int bid, const int j)
{
    const int lane = j & 63, w = j >> 6;
    const int KF = MODE ? 4 : 2;
    const int KREAL = MODE ? 100 : 64;
    const int OG = 4 * H;

    f16x8 bf[4][4];
    #pragma unroll
    for (int g = 0; g < 4; ++g)
        #pragma unroll
        for (int q = 0; q < 4; ++q)
            if (q < KF) bf[g][q] = load_bfrag(W, H, OG, KREAL, w * 16, g, q, lane);

    float bv[4];
    #pragma unroll
    for (int g = 0; g < 4; ++g) {
        const int u = w * 16 + (lane & 15);
        bv[g] = (u < H) ? bias[g * H + u] : 0.0f;
    }

    const int ci = lane & 15, hi = lane >> 4;
    #pragma unroll
    for (int it = 0; it < NIT; ++it) {
        const int m = bid * NIT + it;
        const int bt = m / TCH, tc = m % TCH;

        f16x8 af[4];
        if (MODE == 0) {
            const int b = bt * 16 + ci;
            const int t = ch * TCH + tc;
            #pragma unroll
            for (int q = 0; q < 2; ++q) {
                const int k0 = q * 32 + hi * 8;
                const float* p = Af + ((size_t)b * T_ + t) * F_ + k0;
                float4 x0 = *(const float4*)p;
                float4 x1 = *(const float4*)(p + 4);
                uint4 r;
                r.x = pk2(x0.x, x0.y); r.y = pk2(x0.z, x0.w);
                r.z = pk2(x1.x, x1.y); r.w = pk2(x1.z, x1.w);
                af[q] = __builtin_bit_cast(f16x8, r);
            }
        } else {
            #pragma unroll
            for (int q = 0; q < 4; ++q) {
                const int k0 = q * 32 + hi * 8;
                const size_t base = ((size_t)(bt * TCH + tc) * KP + k0) * 16 + ci;
                f16x8 a;
                #pragma unroll
                for (int e = 0; e < 8; ++e) a[e] = Ah[base + (size_t)e * 16];
                af[q] = a;
            }
        }

        f32x4 acc[4];
        #pragma unroll
        for (int g = 0; g < 4; ++g) { acc[g][0]=bv[g]; acc[g][1]=bv[g]; acc[g][2]=bv[g]; acc[g][3]=bv[g]; }
        #pragma unroll
        for (int g = 0; g < 4; ++g)
            #pragma unroll
            for (int q = 0; q < 4; ++q)
                if (q < KF) acc[g] = mfma16(af[q], bf[g][q], acc[g]);

        #pragma unroll
        for (int g = 0; g < 4; ++g) {
            const int c = (w * 4 + g) * 16 + ci;
            const size_t o = ((size_t)(bt * TCH + tc) * NPC + c) * 16 + hi * 4;
            uint2 s;
            s.x = pk2(acc[g][0], acc[g][1]);
            s.y = pk2(acc[g][2], acc[g][3]);
            *(uint2*)(xp + o) = s;
        }
    }
}

template<int MODE, int NIT>
__global__ __launch_bounds__(512) void k_dense(
    const float* __restrict__ Af, const h16* __restrict__ Ah,
    const float* __restrict__ W, const float* __restrict__ bias,
    const int H, const int ch, h16* __restrict__ xp)
{
    dense_body<MODE, NIT>(Af, Ah, W, bias, H, ch, xp, blockIdx.x, threadIdx.x);
}

// ================= recurrence body =================
// Weights from PREPACKED Uf: 16 coalesced loads (R17 change). Inner loop = R16.
#define LF(G,Q) f16x8 wf##G##Q = *(const f16x8*)(Uf + (size_t)(((w*4+G)*4+Q)*64 + lane)*8);

#define RSTEP(Pn, tcur)                                                          \
    {                                                                            \
        const int t_ = (tcur);                                                   \
        const h16* hb = &hbuf[t_ & 1][0][0];                                     \
        f16x8 a0 = *(const f16x8*)(hb + ci * 136 + 0  + hi * 8);                 \
        f16x8 a1 = *(const f16x8*)(hb + ci * 136 + 32 + hi * 8);                 \
        f16x8 a2 = *(const f16x8*)(hb + ci * 136 + 64 + hi * 8);                 \
        f16x8 a3 = *(const f16x8*)(hb + ci * 136 + 96 + hi * 8);                 \
        f32x4 z0 = up4(Pn##0), z1 = up4(Pn##1), z2 = up4(Pn##2), z3 = up4(Pn##3);\
        const uint to_ = (uint)((t_ + 2 < TCH) ? t_ + 2 : t_) * xstep;           \
        Pn##0 = *(const uint2*)(xp + xb0 + to_);                                 \
        Pn##1 = *(const uint2*)(xp + xb1 + to_);                                 \
        Pn##2 = *(const uint2*)(xp + xb2 + to_);                                 \
        Pn##3 = *(const uint2*)(xp + xb3 + to_);                                 \
        z0 = mfma16(a0, wf00, z0); z0 = mfma16(a1, wf01, z0);                    \
        z0 = mfma16(a2, wf02, z0); z0 = mfma16(a3, wf03, z0);                    \
        z1 = mfma16(a0, wf10, z1); z1 = mfma16(a1, wf11, z1);                    \
        z1 = mfma16(a2, wf12, z1); z1 = mfma16(a3, wf13, z1);                    \
        z2 = mfma16(a0, wf20, z2); z2 = mfma16(a1, wf21, z2);                    \
        z2 = mfma16(a2, wf22, z2); z2 = mfma16(a3, wf23, z2);                    \
        z3 = mfma16(a0, wf30, z3); z3 = mfma16(a1, wf31, z3);                    \
        z3 = mfma16(a2, wf32, z3); z3 = mfma16(a3, wf33, z3);                    \
        f32x4 hv;                                                                \
        _Pragma("unroll")                                                        \
        for (int i = 0; i < 4; ++i) {                                            \
            float ig = sigm(z0[i]);                                              \
            float fg = sigm(z1[i]);                                              \
            float gg = fmaxf(z2[i], 0.0f);                                       \
            float og = sigm(z3[i]);                                              \
            c[i] = fg * c[i] + ig * gg;                                          \
            hv[i] = og * fmaxf(c[i], 0.0f);                                      \
        }                                                                        \
        h16 h0 = (h16)hv[0], h1 = (h16)hv[1], h2 = (h16)hv[2], h3 = (h16)hv[3]; \
        const int nb_ = (t_ & 1) ^ 1;                                            \
        hbuf[nb_][r0 + 0][myu] = h0;                                             \
        hbuf[nb_][r0 + 1][myu] = h1;                                             \
        hbuf[nb_][r0 + 2][myu] = h2;                                             \
        hbuf[nb_][r0 + 3][myu] = h3;                                             \
        h16x2 p01_; p01_.x = h0; p01_.y = h1;                                    \
        h16x2 p23_; p23_.x = h2; p23_.y = h3;                                    \
        hp.x = __builtin_bit_cast(uint, p01_);                                   \
        hp.y = __builtin_bit_cast(uint, p23_);                                   \
        if (do_hout) *(uint2*)(hout + hob + (uint)t_ * hstep) = hp;              \
        bar_lgkm();                                                              \
    }

__device__ __forceinline__ void rec_body(
    const h16* __restrict__ Uf,
    const h16* __restrict__ xp, h16* __restrict__ hout, const int do_hout,
    float* __restrict__ cstate, h16* __restrict__ hstate, const int ch,
    const int bt, const int j)
{
    __shared__ h16 hbuf[2][16][136];
    const int lane = j & 63, w = j >> 6;
    const int ci = lane & 15, hi = lane >> 4;
    const int myu = w * 16 + ci;
    const int r0 = hi * 4;

    LF(0,0) LF(0,1) LF(0,2) LF(0,3)
    LF(1,0) LF(1,1) LF(1,2) LF(1,3)
    LF(2,0) LF(2,1) LF(2,2) LF(2,3)
    LF(3,0) LF(3,1) LF(3,2) LF(3,3)

    {
        const int u = j & 127, rr = (j >> 7) * 4;
        #pragma unroll
        for (int i = 0; i < 4; ++i) {
            h16 v = (h16)0.0f;
            if (ch != 0) v = hstate[((size_t)bt * KP + u) * 16 + rr + i];
            hbuf[0][rr + i][u] = v;
        }
    }
    f32x4 c;
    const size_t coff = ((size_t)bt * KP + myu) * 16 + r0;
    if (ch == 0) { c[0]=0.f; c[1]=0.f; c[2]=0.f; c[3]=0.f; }
    else         { c = *(const f32x4*)(cstate + coff); }
    __syncthreads();

    const uint xstep = NPC * 16;
    const uint xb0 = (uint)(((size_t)bt * TCH) * NPC + (w * 64 + ci)) * 16 + r0;
    const uint xb1 = xb0 + 16 * 16, xb2 = xb0 + 32 * 16, xb3 = xb0 + 48 * 16;

    // prefetch ring depth 2
    uint2 pA0 = *(const uint2*)(xp + xb0);
    uint2 pA1 = *(const uint2*)(xp + xb1);
    uint2 pA2 = *(const uint2*)(xp + xb2);
    uint2 pA3 = *(const uint2*)(xp + xb3);
    uint2 pB0 = *(const uint2*)(xp + xb0 + xstep);
    uint2 pB1 = *(const uint2*)(xp + xb1 + xstep);
    uint2 pB2 = *(const uint2*)(xp + xb2 + xstep);
    uint2 pB3 = *(const uint2*)(xp + xb3 + xstep);

    const uint hstep = KP * 16;
    const uint hob = (uint)(((size_t)bt * TCH) * KP + myu) * 16 + r0;

    uint2 hp; hp.x = 0u; hp.y = 0u;

    for (int tt = 0; tt < TCH; tt += 2) {
        RSTEP(pA, tt)
        RSTEP(pB, tt + 1)
    }

    *(f32x4*)(cstate + coff) = c;
    *(uint2*)(hstate + ((size_t)bt * KP + myu) * 16 + r0) = hp;
}

__global__ __launch_bounds__(512) void k_rec_single(
    const h16* __restrict__ Uf,
    const h16* __restrict__ xp, h16* __restrict__ hout, const int do_hout,
    float* __restrict__ cstate, h16* __restrict__ hstate, const int ch)
{
    rec_body(Uf, xp, hout, do_hout, cstate, hstate, ch, blockIdx.x, threadIdx.x);
}

// MID tier: pair only
__global__ __launch_bounds__(512) void k_rec_pair(
    const h16* __restrict__ UfA, const h16* __restrict__ xpA,
    h16* __restrict__ houtA, const int dohA, float* __restrict__ csA,
    h16* __restrict__ hsA, const int chA,
    const h16* __restrict__ UfB, const h16* __restrict__ xpB,
    h16* __restrict__ houtB, const int dohB, float* __restrict__ csB,
    h16* __restrict__ hsB, const int chB)
{
    const int role = blockIdx.x >> 4;
    const int bt = blockIdx.x & 15;
    rec_body(role ? UfB : UfA, role ? xpB : xpA,
             role ? houtB : houtA, role ? dohB : dohA,
             role ? csB : csA, role ? hsB : hsA, role ? chB : chA,
             bt, threadIdx.x);
}

// FULL tier: rec1(0) prologue (16 blocks) + dense1(1) rider (256 blocks)
__global__ __launch_bounds__(512) void k_rec1_d1(
    const h16* __restrict__ Uf,
    const h16* __restrict__ xp, h16* __restrict__ hout,
    float* __restrict__ cstate, h16* __restrict__ hstate,
    const float* __restrict__ x, const float* __restrict__ W1,
    const float* __restrict__ b1, const int ch_d, h16* __restrict__ xp_d)
{
    if (blockIdx.x < 16) {
        rec_body(Uf, xp, hout, 1, cstate, hstate, 0, blockIdx.x, threadIdx.x);
    } else {
        dense_body<0, 4>(x, (const h16*)nullptr, W1, b1, H1_, ch_d, xp_d,
                         blockIdx.x - 16, threadIdx.x);
    }
}

// FULL tier: rec pair (32 blocks) + optional dense1(ch+2) rider (256 blocks)
__global__ __launch_bounds__(512) void k_pair_d1(
    const h16* __restrict__ UfA, const h16* __restrict__ xpA,
    h16* __restrict__ houtA, const int dohA, float* __restrict__ csA,
    h16* __restrict__ hsA, const int chA,
    const h16* __restrict__ UfB, const h16* __restrict__ xpB,
    h16* __restrict__ houtB, const int dohB, float* __restrict__ csB,
    h16* __restrict__ hsB, const int chB,
    const float* __restrict__ x, const float* __restrict__ W1,
    const float* __restrict__ b1, const int ch_d, h16* __restrict__ xp_d,
    const int do_dense)
{
    if (blockIdx.x < 32) {
        const int role = blockIdx.x >> 4;
        const int bt = blockIdx.x & 15;
        rec_body(role ? UfB : UfA, role ? xpB : xpA,
                 role ? houtB : houtA, role ? dohB : dohA,
                 role ? csB : csA, role ? hsB : hsA, role ? chB : chA,
                 bt, threadIdx.x);
    } else if (do_dense) {
        dense_body<0, 4>(x, (const h16*)nullptr, W1, b1, H1_, ch_d, xp_d,
                         blockIdx.x - 32, threadIdx.x);
    }
}

// ================= head =================
__global__ void k_head(const h16* __restrict__ h2s, const float* __restrict__ Wd,
                       const float* __restrict__ bd, float* __restrict__ out)
{
    __shared__ float lg[OUT_];
    const int b = blockIdx.x, j = threadIdx.x;
    const int bt = b >> 4, r = b & 15;
    if (j < OUT_) {
        float acc = bd[j];
        for (int u = 0; u < H2_; ++u)
            acc += (float)h2s[((size_t)bt * KP + u) * 16 + r] * Wd[u * OUT_ + j];
        lg[j] = acc;
    }
    __syncthreads();
    if (j < OUT_) {
        float m = -1e30f;
        for (int k = 0; k < OUT_; ++k) m = fmaxf(m, lg[k]);
        float s = 0.0f;
        for (int k = 0; k < OUT_; ++k) s += expf(lg[k] - m);
        out[b * OUT_ + j] = expf(lg[j] - m) / s;
    }
}

// ================= R9 fallback (known-good) =================
#define G1_  400
#define G2_  512
#define FBTC 32
#define FB_XP1  0
#define FB_XP2  0
#define FB_WQ   51200
#define FB_XS   134400
#define FB_W2Q  32768
#define FB_H1C  139264
#define FB_U2Q  32768
#define FB_ZBUF 160000
#define FB_H1PK 162048
#define FB_H2PK 162256
#define FB_H2F  162512
#define FB_LDS  163328

__device__ __forceinline__ float fd2(uint wv, uint hv, float cc) {
#if __has_builtin(__builtin_amdgcn_fdot2)
    return __builtin_amdgcn_fdot2(__builtin_bit_cast(h16x2, wv),
                                  __builtin_bit_cast(h16x2, hv), cc, false);
#else
    h16x2 a = __builtin_bit_cast(h16x2, wv), b = __builtin_bit_cast(h16x2, hv);
    return cc + (float)a.x * (float)b.x + (float)a.y * (float)b.y;
#endif
}

__device__ __forceinline__ void stage_quads(const float* __restrict__ P, const int G,
                                            const int NQ, const int KREAL,
                                            char* dst, const int j)
{
    if (j < G) {
        for (int q = 0; q < NQ; ++q) {
            float f[8];
            #pragma unroll
            for (int r = 0; r < 8; ++r) {
                const int k = 8 * q + r;
                f[r] = (k < KREAL) ? P[(size_t)k * G + j] : 0.0f;
            }
            uint4 u;
            u.x = pk2(f[0], f[1]); u.y = pk2(f[2], f[3]);
            u.z = pk2(f[4], f[5]); u.w = pk2(f[6], f[7]);
            *(uint4*)(dst + (size_t)(q * G + j) * 16) = u;
        }
    }
}

__global__ __launch_bounds__(512) void lstm_fallback(
    const float* __restrict__ x,
    const float* __restrict__ W1, const float* __restrict__ U1, const float* __restrict__ b1,
    const float* __restrict__ W2, const float* __restrict__ U2, const float* __restrict__ b2,
    const float* __restrict__ Wd, const float* __restrict__ bd,
    float* __restrict__ out)
{
    __shared__ uint4 smem4[FB_LDS / 16];
    char* sm = (char*)smem4;
    const int b = blockIdx.x;
    const int j = threadIdx.x;
    float c1 = 0.0f, c2 = 0.0f;

    const uint u2r0 = pk2(U2[120 * G2_ + j], U2[121 * G2_ + j]);
    const uint u2r1 = pk2(U2[122 * G2_ + j], U2[123 * G2_ + j]);
    const uint u2r2 = pk2(U2[124 * G2_ + j], U2[125 * G2_ + j]);
    const uint u2r3 = pk2(U2[126 * G2_ + j], U2[127 * G2_ + j]);

    if (j < 52) *(uint*)(sm + FB_H1PK + 4 * j) = 0u;
    if (j < 64) *(uint*)(sm + FB_H2PK + 4 * j) = 0u;
    __syncthreads();

    const float* xrow = x + (size_t)b * T_ * F_;
    for (int ch = 0; ch < T_ / FBTC; ++ch) {
        stage_quads(W1, G1_, 8, 64, sm + FB_WQ, j);
        #pragma unroll
        for (int r = 0; r < 2; ++r) {
            int v = r * 512 + j;
            float2 xv = *(const float2*)(xrow + ch * (FBTC * F_) + 2 * v);
            *(uint*)(sm + FB_XS + 4 * v) = pk2(xv.x, xv.y);
        }
        __syncthreads();
        if (j < G1_) {
            const float bj = b1[j];
            const uint4* WQ = (const uint4*)(sm + FB_WQ);
            for (int t = 0; t < FBTC; ++t) {
                const uint4* XQ = (const uint4*)(sm + FB_XS + t * 128);
                float a0 = bj, a1 = 0.f, a2 = 0.f, a3 = 0.f;
                #pragma unroll
                for (int q = 0; q < 8; ++q) {
                    uint4 wq = WQ[q * G1_ + j]; uint4 hq = XQ[q];
                    a0 = fd2(wq.x, hq.x, a0); a1 = fd2(wq.y, hq.y, a1);
                    a2 = fd2(wq.z, hq.z, a2); a3 = fd2(wq.w, hq.w, a3);
                }
                *(float*)(sm + FB_XP1 + 4 * (t * G1_ + j)) = (a0 + a1) + (a2 + a3);
            }
        }
        __syncthreads();
        stage_quads(U1, G1_, 13, H1_, sm + FB_WQ, j);
        __syncthreads();
        for (int t = 0; t < FBTC; ++t) {
            if (j < G1_) {
                const uint4* WQ = (const uint4*)(sm + FB_WQ);
                const uint4* HP = (const uint4*)(sm + FB_H1PK);
                float a0 = *(const float*)(sm + FB_XP1 + 4 * (t * G1_ + j));
                float a1 = 0.f, a2 = 0.f, a3 = 0.f;
                #pragma unroll
                for (int q = 0; q < 13; ++q) {
                    uint4 wq = WQ[q * G1_ + j]; uint4 hq = HP[q];
                    a0 = fd2(wq.x, hq.x, a0); a1 = fd2(wq.y, hq.y, a1);
                    a2 = fd2(wq.z, hq.z, a2); a3 = fd2(wq.w, hq.w, a3);
                }
                *(float*)(sm + FB_ZBUF + 4 * j) = (a0 + a1) + (a2 + a3);
            }
            __syncthreads();
            if (j < H1_) {
                const float* zb = (const float*)(sm + FB_ZBUF);
                float ig = sigm(zb[j]);
                float fg = sigm(zb[H1_ + j]);
                float gg = fmaxf(zb[2 * H1_ + j], 0.0f);
                float og = sigm(zb[3 * H1_ + j]);
                c1 = fg * c1 + ig * gg;
                float h = og * fmaxf(c1, 0.0f);
                h16 hh = (h16)h;
                *(h16*)(sm + FB_H1PK + 2 * j) = hh;
                *(h16*)(sm + FB_H1C + t * 208 + 2 * j) = hh;
            }
            __syncthreads();
        }
        stage_quads(W2, G2_, 13, H1_, sm + FB_W2Q, j);
        __syncthreads();
        {
            const float bj = b2[j];
            const uint4* WQ = (const uint4*)(sm + FB_W2Q);
            for (int t = 0; t < FBTC; ++t) {
                const uint4* HC = (const uint4*)(sm + FB_H1C + t * 208);
                float a0 = bj, a1 = 0.f, a2 = 0.f, a3 = 0.f;
                #pragma unroll
                for (int q = 0; q < 13; ++q) {
                    uint4 wq = WQ[q * G2_ + j]; uint4 hq = HC[q];
                    a0 = fd2(wq.x, hq.x, a0); a1 = fd2(wq.y, hq.y, a1);
                    a2 = fd2(wq.z, hq.z, a2); a3 = fd2(wq.w, hq.w, a3);
                }
                *(h16*)(sm + FB_XP2 + 2 * (t * G2_ + j)) = (h16)((a0 + a1) + (a2 + a3));
            }
        }
        __syncthreads();
        stage_quads(U2, G2_, 15, 120, sm + FB_U2Q, j);
        __syncthreads();
        for (int t = 0; t < FBTC; ++t) {
            {
                const uint4* WQ = (const uint4*)(sm + FB_U2Q);
                const uint4* HP = (const uint4*)(sm + FB_H2PK);
                float a0 = (float)*(const h16*)(sm + FB_XP2 + 2 * (t * G2_ + j));
                float a1 = 0.f, a2 = 0.f, a3 = 0.f;
                #pragma unroll
                for (int q = 0; q < 15; ++q) {
                    uint4 wq = WQ[q * G2_ + j]; uint4 hq = HP[q];
                    a0 = fd2(wq.x, hq.x, a0); a1 = fd2(wq.y, hq.y, a1);
                    a2 = fd2(wq.z, hq.z, a2); a3 = fd2(wq.w, hq.w, a3);
                }
                uint4 hp15 = ((const uint4*)(sm + FB_H2PK))[15];
                a0 = fd2(u2r0, hp15.x, a0); a1 = fd2(u2r1, hp15.y, a1);
                a2 = fd2(u2r2, hp15.z, a2); a3 = fd2(u2r3, hp15.w, a3);
                *(float*)(sm + FB_ZBUF + 4 * j) = (a0 + a1) + (a2 + a3);
            }
            __syncthreads();
            if (j < H2_) {
                const float* zb = (const float*)(sm + FB_ZBUF);
                float ig = sigm(zb[j]);
                float fg = sigm(zb[H2_ + j]);
                float gg = fmaxf(zb[2 * H2_ + j], 0.0f);
                float og = sigm(zb[3 * H2_ + j]);
                c2 = fg * c2 + ig * gg;
                float h = og * fmaxf(c2, 0.0f);
                *(h16*)(sm + FB_H2PK + 2 * j) = (h16)h;
                *(float*)(sm + FB_H2F + 4 * j) = h;
            }
            __syncthreads();
        }
    }
    if (j < OUT_) {
        const float* h2 = (const float*)(sm + FB_H2F);
        float acc = bd[j];
        #pragma unroll
        for (int k = 0; k < H2_; ++k) acc += h2[k] * Wd[k * OUT_ + j];
        *(float*)(sm + FB_ZBUF + 4 * j) = acc;
    }
    __syncthreads();
    if (j < OUT_) {
        const float* zb = (const float*)(sm + FB_ZBUF);
        float m = -1e30f;
        for (int k = 0; k < OUT_; ++k) m = fmaxf(m, zb[k]);
        float s = 0.0f;
        for (int k = 0; k < OUT_; ++k) s += expf(zb[k] - m);
        out[b * OUT_ + j] = expf(zb[j] - m) / s;
    }
}

// ================= launcher =================
extern "C" void kernel_launch(void* const* d_in, const int* in_sizes, int n_in,
                              void* d_out, int out_size, void* d_ws, size_t ws_size,
                              hipStream_t stream) {
    const float* x  = (const float*)d_in[0];
    const float* W1 = (const float*)d_in[1];
    const float* U1 = (const float*)d_in[2];
    const float* b1 = (const float*)d_in[3];
    const float* W2 = (const float*)d_in[4];
    const float* U2 = (const float*)d_in[5];
    const float* b2 = (const float*)d_in[6];
    const float* Wd = (const float*)d_in[7];
    const float* bd = (const float*)d_in[8];
    float* out = (float*)d_out;

    if (ws_size >= WS_FULL) {
        char* ws = (char*)d_ws;
        h16*   xp1a = (h16*)(ws + F_XP1A);
        h16*   xp1b = (h16*)(ws + F_XP1B);
        h16*   xp2  = (h16*)(ws + F_XP2);
        h16*   h1g  = (h16*)(ws + F_H1G);
        float* c1   = (float*)(ws + F_C1);
        float* c2   = (float*)(ws + F_C2);
        h16*   h1s  = (h16*)(ws + F_H1S);
        h16*   h2s  = (h16*)(ws + F_H2S);
        h16*   u1f  = (h16*)(ws + F_U1F);
        h16*   u2f  = (h16*)(ws + F_U2F);
        h16* xp1[2] = { xp1a, xp1b };

        k_prepack<<<16, 512, 0, stream>>>(U1, U2, u1f, u2f);
        k_dense<0, 4><<<256, 512, 0, stream>>>(x, (const h16*)nullptr, W1, b1, H1_, 0, xp1[0]);
        k_rec1_d1<<<272, 512, 0, stream>>>(u1f, xp1[0], h1g, c1, h1s,
                                           x, W1, b1, 1, xp1[1]);

        for (int ch = 0; ch < NCH; ++ch) {
            k_dense<1, 4><<<256, 512, 0, stream>>>((const float*)nullptr, h1g, W2, b2, H2_, ch, xp2);
            if (ch + 1 < NCH) {
                const int dd = (ch + 2 < NCH) ? 1 : 0;
                k_pair_d1<<<288, 512, 0, stream>>>(
                    u2f, xp2, (h16*)nullptr, 0, c2, h2s, ch,
                    u1f, xp1[(ch + 1) & 1], h1g, 1, c1, h1s, ch + 1,
                    x, W1, b1, ch + 2, xp1[ch & 1], dd);
            } else {
                k_rec_single<<<16, 512, 0, stream>>>(u2f, xp2, (h16*)nullptr, 0, c2, h2s, ch);
            }
        }
        k_head<<<256, 64, 0, stream>>>(h2s, Wd, bd, out);
    } else if (ws_size >= WS_MID) {
        char* ws = (char*)d_ws;
        h16*   xp1 = (h16*)(ws + M_XP1);
        h16*   xp2 = (h16*)(ws + M_XP2);
        h16*   h1g = (h16*)(ws + M_H1G);
        float* c1  = (float*)(ws + M_C1);
        float* c2  = (float*)(ws + M_C2);
        h16*   h1s = (h16*)(ws + M_H1S);
        h16*   h2s = (h16*)(ws + M_H2S);
        h16*   u1f = (h16*)(ws + M_U1F);
        h16*   u2f = (h16*)(ws + M_U2F);

        k_prepack<<<16, 512, 0, stream>>>(U1, U2, u1f, u2f);
        k_dense<0, 4><<<256, 512, 0, stream>>>(x, (const h16*)nullptr, W1, b1, H1_, 0, xp1);
        k_rec_single<<<16, 512, 0, stream>>>(u1f, xp1, h1g, 1, c1, h1s, 0);

        for (int ch = 0; ch < NCH; ++ch) {
            k_dense<1, 4><<<256, 512, 0, stream>>>((const float*)nullptr, h1g, W2, b2, H2_, ch, xp2);
            if (ch + 1 < NCH) {
                k_dense<0, 4><<<256, 512, 0, stream>>>(x, (const h16*)nullptr, W1, b1, H1_, ch + 1, xp1);
                k_rec_pair<<<32, 512, 0, stream>>>(
                    u2f, xp2, (h16*)nullptr, 0, c2, h2s, ch,
                    u1f, xp1, h1g,           1, c1, h1s, ch + 1);
            } else {
                k_rec_single<<<16, 512, 0, stream>>>(u2f, xp2, (h16*)nullptr, 0, c2, h2s, ch);
            }
        }
        k_head<<<256, 64, 0, stream>>>(h2s, Wd, bd, out);
    } else {
        lstm_fallback<<<B_, 512, 0, stream>>>(x, W1, U1, b1, W2, U2, b2, Wd, bd, out);
    }
}

// Round 18
// 795.087 us; speedup vs baseline: 2.6613x; 1.2232x over previous
//
#include <hip/hip_runtime.h>
#include <math.h>

// Problem dims
#define B_   256
#define T_   512
#define F_   64
#define H1_  100
#define H2_  128
#define OUT_ 19
#define TCH  64             // timesteps per chunk (pipeline stage)
#define NCH  (T_/TCH)       // 8 chunks
#define NPC  512            // padded+permuted gate columns (both layers)
#define KP   128            // padded K (units) for both layers

typedef unsigned int uint;
typedef _Float16 h16;
typedef __attribute__((ext_vector_type(2))) _Float16 h16x2;
typedef __attribute__((ext_vector_type(8))) _Float16 f16x8;
typedef __attribute__((ext_vector_type(4))) float f32x4;

// ---- workspace layouts (bytes) ----
#define XPW_BYTES (16ull*TCH*NPC*16*2)     // 16,777,216 per xp buffer
#define H1G_BYTES (16ull*TCH*KP*16*2)      // 4,194,304 per h1g buffer
#define CST_BYTES (16ull*KP*16*4)          // 131,072
#define HST_BYTES (16ull*KP*16*2)          // 65,536
#define UF_BYTES  (128ull*64*8*2)          // 131,072 per packed-U buffer

// TIER A: lead-2 pipeline, everything ring-2 (~76.2 MB)
#define A_XP1A  0ull
#define A_XP1B  (A_XP1A + XPW_BYTES)
#define A_XP2A  (A_XP1B + XPW_BYTES)
#define A_XP2B  (A_XP2A + XPW_BYTES)
#define A_H1GA  (A_XP2B + XPW_BYTES)
#define A_H1GB  (A_H1GA + H1G_BYTES)
#define A_C1    (A_H1GB + H1G_BYTES)
#define A_C2    (A_C1   + CST_BYTES)
#define A_H1S   (A_C2   + CST_BYTES)
#define A_H2S   (A_H1S  + HST_BYTES)
#define A_U1F   (A_H2S  + HST_BYTES)
#define A_U2F   (A_U1F  + UF_BYTES)
#define WS_A    (A_U2F  + UF_BYTES)        // ~76.2 MB

// TIER B: R17 proven schedule (~55.2 MB): xp1 ring-2, xp2+h1g single
#define B_XP1A  0ull
#define B_XP1B  (B_XP1A + XPW_BYTES)
#define B_XP2   (B_XP1B + XPW_BYTES)
#define B_H1G   (B_XP2  + XPW_BYTES)
#define B_C1    (B_H1G  + H1G_BYTES)
#define B_C2    (B_C1   + CST_BYTES)
#define B_H1S   (B_C2   + CST_BYTES)
#define B_H2S   (B_H1S  + HST_BYTES)
#define B_U1F   (B_H2S  + HST_BYTES)
#define B_U2F   (B_U1F  + UF_BYTES)
#define WS_B    (B_U2F  + UF_BYTES)        // ~55.2 MB

__device__ __forceinline__ float sigm(float x) { return 1.0f / (1.0f + __expf(-x)); }

__device__ __forceinline__ uint pk2(float a, float b) {
    h16x2 h; h.x = (h16)a; h.y = (h16)b;
    return __builtin_bit_cast(uint, h);
}

__device__ __forceinline__ f32x4 mfma16(f16x8 a, f16x8 b, f32x4 c) {
    return __builtin_amdgcn_mfma_f32_16x16x32_f16(a, b, c, 0, 0, 0);
}

__device__ __forceinline__ f32x4 up4(uint2 v) {
    h16x2 a = __builtin_bit_cast(h16x2, v.x);
    h16x2 b = __builtin_bit_cast(h16x2, v.y);
    f32x4 r; r[0] = (float)a.x; r[1] = (float)a.y; r[2] = (float)b.x; r[3] = (float)b.y;
    return r;
}

// lgkm-only barrier (T4): orders LDS h-exchange without draining vmcnt.
__device__ __forceinline__ void bar_lgkm() {
    asm volatile("s_waitcnt lgkmcnt(0)" ::: "memory");
    __builtin_amdgcn_sched_barrier(0);
    __builtin_amdgcn_s_barrier();
    __builtin_amdgcn_sched_barrier(0);
}

// B-fragment loader with gate-column permutation (strided; used by dense + prepack).
__device__ __forceinline__ f16x8 load_bfrag(const float* __restrict__ P, int H, int OG,
                                            int Kreal, int ubase, int g, int q, int lane) {
    const int u  = ubase + (lane & 15);
    const int k0 = q * 32 + (lane >> 4) * 8;
    const int col = g * H + u;
    float f[8];
    #pragma unroll
    for (int e = 0; e < 8; ++e) {
        const int k = k0 + e;
        f[e] = (u < H && k < Kreal) ? P[(size_t)k * OG + col] : 0.0f;
    }
    uint4 r;
    r.x = pk2(f[0], f[1]); r.y = pk2(f[2], f[3]);
    r.z = pk2(f[4], f[5]); r.w = pk2(f[6], f[7]);
    return __builtin_bit_cast(f16x8, r);
}

// ================= weight prepack (runs once) =================
__global__ __launch_bounds__(512) void k_prepack(
    const float* __restrict__ U1, const float* __restrict__ U2,
    h16* __restrict__ U1f, h16* __restrict__ U2f)
{
    const int w = blockIdx.x & 7;
    const int layer = blockIdx.x >> 3;
    const float* U = layer ? U2 : U1;
    const int H = layer ? H2_ : H1_;
    h16* Uf = layer ? U2f : U1f;
    const int lane = threadIdx.x & 63;
    #pragma unroll
    for (int it = 0; it < 2; ++it) {
        const int combo = it * 8 + (threadIdx.x >> 6);
        const int g = combo >> 2, q = combo & 3;
        f16x8 fr = load_bfrag(U, H, 4 * H, H, w * 16, g, q, lane);
        *(f16x8*)(Uf + (size_t)(((w * 4 + g) * 4 + q) * 64 + lane) * 8) = fr;
    }
}

// ================= dense pre-projection body =================
template<int MODE, int NIT>
__device__ __forceinline__ void dense_body(
    const float* __restrict__ Af, const h16* __restrict__ Ah,
    const float* __restrict__ W, const float* __restrict__ bias,
    const int H, const int ch, h16* __restrict__ xp,
    const int bid, const int j)
{
    const int lane = j & 63, w = j >> 6;
    const int KF = MODE ? 4 : 2;
    const int KREAL = MODE ? 100 : 64;
    const int OG = 4 * H;

    f16x8 bf[4][4];
    #pragma unroll
    for (int g = 0; g < 4; ++g)
        #pragma unroll
        for (int q = 0; q < 4; ++q)
            if (q < KF) bf[g][q] = load_bfrag(W, H, OG, KREAL, w * 16, g, q, lane);

    float bv[4];
    #pragma unroll
    for (int g = 0; g < 4; ++g) {
        const int u = w * 16 + (lane & 15);
        bv[g] = (u < H) ? bias[g * H + u] : 0.0f;
    }

    const int ci = lane & 15, hi = lane >> 4;
    #pragma unroll
    for (int it = 0; it < NIT; ++it) {
        const int m = bid * NIT + it;
        const int bt = m / TCH, tc = m % TCH;

        f16x8 af[4];
        if (MODE == 0) {
            const int b = bt * 16 + ci;
            const int t = ch * TCH + tc;
            #pragma unroll
            for (int q = 0; q < 2; ++q) {
                const int k0 = q * 32 + hi * 8;
                const float* p = Af + ((size_t)b * T_ + t) * F_ + k0;
                float4 x0 = *(const float4*)p;
                float4 x1 = *(const float4*)(p + 4);
                uint4 r;
                r.x = pk2(x0.x, x0.y); r.y = pk2(x0.z, x0.w);
                r.z = pk2(x1.x, x1.y); r.w = pk2(x1.z, x1.w);
                af[q] = __builtin_bit_cast(f16x8, r);
            }
        } else {
            #pragma unroll
            for (int q = 0; q < 4; ++q) {
                const int k0 = q * 32 + hi * 8;
                const size_t base = ((size_t)(bt * TCH + tc) * KP + k0) * 16 + ci;
                f16x8 a;
                #pragma unroll
                for (int e = 0; e < 8; ++e) a[e] = Ah[base + (size_t)e * 16];
                af[q] = a;
            }
        }

        f32x4 acc[4];
        #pragma unroll
        for (int g = 0; g < 4; ++g) { acc[g][0]=bv[g]; acc[g][1]=bv[g]; acc[g][2]=bv[g]; acc[g][3]=bv[g]; }
        #pragma unroll
        for (int g = 0; g < 4; ++g)
            #pragma unroll
            for (int q = 0; q < 4; ++q)
                if (q < KF) acc[g] = mfma16(af[q], bf[g][q], acc[g]);

        #pragma unroll
        for (int g = 0; g < 4; ++g) {
            const int c = (w * 4 + g) * 16 + ci;
            const size_t o = ((size_t)(bt * TCH + tc) * NPC + c) * 16 + hi * 4;
            uint2 s;
            s.x = pk2(acc[g][0], acc[g][1]);
            s.y = pk2(acc[g][2], acc[g][3]);
            *(uint2*)(xp + o) = s;
        }
    }
}

template<int MODE, int NIT>
__global__ __launch_bounds__(512) void k_dense(
    const float* __restrict__ Af, const h16* __restrict__ Ah,
    const float* __restrict__ W, const float* __restrict__ bias,
    const int H, const int ch, h16* __restrict__ xp)
{
    dense_body<MODE, NIT>(Af, Ah, W, bias, H, ch, xp, blockIdx.x, threadIdx.x);
}

// ================= recurrence body (R17, unchanged) =================
#define LF(G,Q) f16x8 wf##G##Q = *(const f16x8*)(Uf + (size_t)(((w*4+G)*4+Q)*64 + lane)*8);

#define RSTEP(Pn, tcur)                                                          \
    {                                                                            \
        const int t_ = (tcur);                                                   \
        const h16* hb = &hbuf[t_ & 1][0][0];                                     \
        f16x8 a0 = *(const f16x8*)(hb + ci * 136 + 0  + hi * 8);                 \
        f16x8 a1 = *(const f16x8*)(hb + ci * 136 + 32 + hi * 8);                 \
        f16x8 a2 = *(const f16x8*)(hb + ci * 136 + 64 + hi * 8);                 \
        f16x8 a3 = *(const f16x8*)(hb + ci * 136 + 96 + hi * 8);                 \
        f32x4 z0 = up4(Pn##0), z1 = up4(Pn##1), z2 = up4(Pn##2), z3 = up4(Pn##3);\
        const uint to_ = (uint)((t_ + 2 < TCH) ? t_ + 2 : t_) * xstep;           \
        Pn##0 = *(const uint2*)(xp + xb0 + to_);                                 \
        Pn##1 = *(const uint2*)(xp + xb1 + to_);                                 \
        Pn##2 = *(const uint2*)(xp + xb2 + to_);                                 \
        Pn##3 = *(const uint2*)(xp + xb3 + to_);                                 \
        z0 = mfma16(a0, wf00, z0); z0 = mfma16(a1, wf01, z0);                    \
        z0 = mfma16(a2, wf02, z0); z0 = mfma16(a3, wf03, z0);                    \
        z1 = mfma16(a0, wf10, z1); z1 = mfma16(a1, wf11, z1);                    \
        z1 = mfma16(a2, wf12, z1); z1 = mfma16(a3, wf13, z1);                    \
        z2 = mfma16(a0, wf20, z2); z2 = mfma16(a1, wf21, z2);                    \
        z2 = mfma16(a2, wf22, z2); z2 = mfma16(a3, wf23, z2);                    \
        z3 = mfma16(a0, wf30, z3); z3 = mfma16(a1, wf31, z3);                    \
        z3 = mfma16(a2, wf32, z3); z3 = mfma16(a3, wf33, z3);                    \
        f32x4 hv;                                                                \
        _Pragma("unroll")                                                        \
        for (int i = 0; i < 4; ++i) {                                            \
            float ig = sigm(z0[i]);                                              \
            float fg = sigm(z1[i]);                                              \
            float gg = fmaxf(z2[i], 0.0f);                                       \
            float og = sigm(z3[i]);                                              \
            c[i] = fg * c[i] + ig * gg;                                          \
            hv[i] = og * fmaxf(c[i], 0.0f);                                      \
        }                                                                        \
        h16 h0 = (h16)hv[0], h1 = (h16)hv[1], h2 = (h16)hv[2], h3 = (h16)hv[3]; \
        const int nb_ = (t_ & 1) ^ 1;                                            \
        hbuf[nb_][r0 + 0][myu] = h0;                                             \
        hbuf[nb_][r0 + 1][myu] = h1;                                             \
        hbuf[nb_][r0 + 2][myu] = h2;                                             \
        hbuf[nb_][r0 + 3][myu] = h3;                                             \
        h16x2 p01_; p01_.x = h0; p01_.y = h1;                                    \
        h16x2 p23_; p23_.x = h2; p23_.y = h3;                                    \
        hp.x = __builtin_bit_cast(uint, p01_);                                   \
        hp.y = __builtin_bit_cast(uint, p23_);                                   \
        if (do_hout) *(uint2*)(hout + hob + (uint)t_ * hstep) = hp;              \
        bar_lgkm();                                                              \
    }

__device__ __forceinline__ void rec_body(
    const h16* __restrict__ Uf,
    const h16* __restrict__ xp, h16* __restrict__ hout, const int do_hout,
    float* __restrict__ cstate, h16* __restrict__ hstate, const int ch,
    const int bt, const int j)
{
    __shared__ h16 hbuf[2][16][136];
    const int lane = j & 63, w = j >> 6;
    const int ci = lane & 15, hi = lane >> 4;
    const int myu = w * 16 + ci;
    const int r0 = hi * 4;

    LF(0,0) LF(0,1) LF(0,2) LF(0,3)
    LF(1,0) LF(1,1) LF(1,2) LF(1,3)
    LF(2,0) LF(2,1) LF(2,2) LF(2,3)
    LF(3,0) LF(3,1) LF(3,2) LF(3,3)

    {
        const int u = j & 127, rr = (j >> 7) * 4;
        #pragma unroll
        for (int i = 0; i < 4; ++i) {
            h16 v = (h16)0.0f;
            if (ch != 0) v = hstate[((size_t)bt * KP + u) * 16 + rr + i];
            hbuf[0][rr + i][u] = v;
        }
    }
    f32x4 c;
    const size_t coff = ((size_t)bt * KP + myu) * 16 + r0;
    if (ch == 0) { c[0]=0.f; c[1]=0.f; c[2]=0.f; c[3]=0.f; }
    else         { c = *(const f32x4*)(cstate + coff); }
    __syncthreads();

    const uint xstep = NPC * 16;
    const uint xb0 = (uint)(((size_t)bt * TCH) * NPC + (w * 64 + ci)) * 16 + r0;
    const uint xb1 = xb0 + 16 * 16, xb2 = xb0 + 32 * 16, xb3 = xb0 + 48 * 16;

    uint2 pA0 = *(const uint2*)(xp + xb0);
    uint2 pA1 = *(const uint2*)(xp + xb1);
    uint2 pA2 = *(const uint2*)(xp + xb2);
    uint2 pA3 = *(const uint2*)(xp + xb3);
    uint2 pB0 = *(const uint2*)(xp + xb0 + xstep);
    uint2 pB1 = *(const uint2*)(xp + xb1 + xstep);
    uint2 pB2 = *(const uint2*)(xp + xb2 + xstep);
    uint2 pB3 = *(const uint2*)(xp + xb3 + xstep);

    const uint hstep = KP * 16;
    const uint hob = (uint)(((size_t)bt * TCH) * KP + myu) * 16 + r0;

    uint2 hp; hp.x = 0u; hp.y = 0u;

    for (int tt = 0; tt < TCH; tt += 2) {
        RSTEP(pA, tt)
        RSTEP(pB, tt + 1)
    }

    *(f32x4*)(cstate + coff) = c;
    *(uint2*)(hstate + ((size_t)bt * KP + myu) * 16 + r0) = hp;
}

// ================= unified mega-dispatch =================
// blocks 0-15: rec2 | 16-31: rec1 | 32-287: dense2 rider | 288-543: dense1 rider
__global__ __launch_bounds__(512) void k_mega(
    const int rec2_on, const h16* __restrict__ Uf2, const h16* __restrict__ xp2r,
    float* __restrict__ c2, h16* __restrict__ hs2, const int ch2,
    const int rec1_on, const h16* __restrict__ Uf1, const h16* __restrict__ xp1r,
    h16* __restrict__ h1gw, float* __restrict__ c1, h16* __restrict__ hs1, const int ch1,
    const int d2_on, const h16* __restrict__ h1gr, const float* __restrict__ W2,
    const float* __restrict__ b2, h16* __restrict__ xp2w,
    const int d1_on, const float* __restrict__ x, const float* __restrict__ W1,
    const float* __restrict__ b1, const int chd1, h16* __restrict__ xp1w)
{
    const int bid = blockIdx.x, j = threadIdx.x;
    if (bid < 16) {
        if (rec2_on) rec_body(Uf2, xp2r, (h16*)nullptr, 0, c2, hs2, ch2, bid, j);
    } else if (bid < 32) {
        if (rec1_on) rec_body(Uf1, xp1r, h1gw, 1, c1, hs1, ch1, bid - 16, j);
    } else if (bid < 288) {
        if (d2_on) dense_body<1, 4>((const float*)nullptr, h1gr, W2, b2, H2_, 0, xp2w, bid - 32, j);
    } else {
        if (d1_on) dense_body<0, 4>(x, (const h16*)nullptr, W1, b1, H1_, chd1, xp1w, bid - 288, j);
    }
}

// ================= head =================
__global__ void k_head(const h16* __restrict__ h2s, const float* __restrict__ Wd,
                       const float* __restrict__ bd, float* __restrict__ out)
{
    __shared__ float lg[OUT_];
    const int b = blockIdx.x, j = threadIdx.x;
    const int bt = b >> 4, r = b & 15;
    if (j < OUT_) {
        float acc = bd[j];
        for (int u = 0; u < H2_; ++u)
            acc += (float)h2s[((size_t)bt * KP + u) * 16 + r] * Wd[u * OUT_ + j];
        lg[j] = acc;
    }
    __syncthreads();
    if (j < OUT_) {
        float m = -1e30f;
        for (int k = 0; k < OUT_; ++k) m = fmaxf(m, lg[k]);
        float s = 0.0f;
        for (int k = 0; k < OUT_; ++k) s += expf(lg[k] - m);
        out[b * OUT_ + j] = expf(lg[j] - m) / s;
    }
}

// ================= R9 fallback (known-good) =================
#define G1_  400
#define G2_  512
#define FBTC 32
#define FB_XP1  0
#define FB_XP2  0
#define FB_WQ   51200
#define FB_XS   134400
#define FB_W2Q  32768
#define FB_H1C  139264
#define FB_U2Q  32768
#define FB_ZBUF 160000
#define FB_H1PK 162048
#define FB_H2PK 162256
#define FB_H2F  162512
#define FB_LDS  163328

__device__ __forceinline__ float fd2(uint wv, uint hv, float cc) {
#if __has_builtin(__builtin_amdgcn_fdot2)
    return __builtin_amdgcn_fdot2(__builtin_bit_cast(h16x2, wv),
                                  __builtin_bit_cast(h16x2, hv), cc, false);
#else
    h16x2 a = __builtin_bit_cast(h16x2, wv), b = __builtin_bit_cast(h16x2, hv);
    return cc + (float)a.x * (float)b.x + (float)a.y * (float)b.y;
#endif
}

__device__ __forceinline__ void stage_quads(const float* __restrict__ P, const int G,
                                            const int NQ, const int KREAL,
                                            char* dst, const int j)
{
    if (j < G) {
        for (int q = 0; q < NQ; ++q) {
            float f[8];
            #pragma unroll
            for (int r = 0; r < 8; ++r) {
                const int k = 8 * q + r;
                f[r] = (k < KREAL) ? P[(size_t)k * G + j] : 0.0f;
            }
            uint4 u;
            u.x = pk2(f[0], f[1]); u.y = pk2(f[2], f[3]);
            u.z = pk2(f[4], f[5]); u.w = pk2(f[6], f[7]);
            *(uint4*)(dst + (size_t)(q * G + j) * 16) = u;
        }
    }
}

__global__ __launch_bounds__(512) void lstm_fallback(
    const float* __restrict__ x,
    const float* __restrict__ W1, const float* __restrict__ U1, const float* __restrict__ b1,
    const float* __restrict__ W2, const float* __restrict__ U2, const float* __restrict__ b2,
    const float* __restrict__ Wd, const float* __restrict__ bd,
    float* __restrict__ out)
{
    __shared__ uint4 smem4[FB_LDS / 16];
    char* sm = (char*)smem4;
    const int b = blockIdx.x;
    const int j = threadIdx.x;
    float c1 = 0.0f, c2 = 0.0f;

    const uint u2r0 = pk2(U2[120 * G2_ + j], U2[121 * G2_ + j]);
    const uint u2r1 = pk2(U2[122 * G2_ + j], U2[123 * G2_ + j]);
    const uint u2r2 = pk2(U2[124 * G2_ + j], U2[125 * G2_ + j]);
    const uint u2r3 = pk2(U2[126 * G2_ + j], U2[127 * G2_ + j]);

    if (j < 52) *(uint*)(sm + FB_H1PK + 4 * j) = 0u;
    if (j < 64) *(uint*)(sm + FB_H2PK + 4 * j) = 0u;
    __syncthreads();

    const float* xrow = x + (size_t)b * T_ * F_;
    for (int ch = 0; ch < T_ / FBTC; ++ch) {
        stage_quads(W1, G1_, 8, 64, sm + FB_WQ, j);
        #pragma unroll
        for (int r = 0; r < 2; ++r) {
            int v = r * 512 + j;
            float2 xv = *(const float2*)(xrow + ch * (FBTC * F_) + 2 * v);
            *(uint*)(sm + FB_XS + 4 * v) = pk2(xv.x, xv.y);
        }
        __syncthreads();
        if (j < G1_) {
            const float bj = b1[j];
            const uint4* WQ = (const uint4*)(sm + FB_WQ);
            for (int t = 0; t < FBTC; ++t) {
                const uint4* XQ = (const uint4*)(sm + FB_XS + t * 128);
                float a0 = bj, a1 = 0.f, a2 = 0.f, a3 = 0.f;
                #pragma unroll
                for (int q = 0; q < 8; ++q) {
                    uint4 wq = WQ[q * G1_ + j]; uint4 hq = XQ[q];
                    a0 = fd2(wq.x, hq.x, a0); a1 = fd2(wq.y, hq.y, a1);
                    a2 = fd2(wq.z, hq.z, a2); a3 = fd2(wq.w, hq.w, a3);
                }
                *(float*)(sm + FB_XP1 + 4 * (t * G1_ + j)) = (a0 + a1) + (a2 + a3);
            }
        }
        __syncthreads();
        stage_quads(U1, G1_, 13, H1_, sm + FB_WQ, j);
        __syncthreads();
        for (int t = 0; t < FBTC; ++t) {
            if (j < G1_) {
                const uint4* WQ = (const uint4*)(sm + FB_WQ);
                const uint4* HP = (const uint4*)(sm + FB_H1PK);
                float a0 = *(const float*)(sm + FB_XP1 + 4 * (t * G1_ + j));
                float a1 = 0.f, a2 = 0.f, a3 = 0.f;
                #pragma unroll
                for (int q = 0; q < 13; ++q) {
                    uint4 wq = WQ[q * G1_ + j]; uint4 hq = HP[q];
                    a0 = fd2(wq.x, hq.x, a0); a1 = fd2(wq.y, hq.y, a1);
                    a2 = fd2(wq.z, hq.z, a2); a3 = fd2(wq.w, hq.w, a3);
                }
                *(float*)(sm + FB_ZBUF + 4 * j) = (a0 + a1) + (a2 + a3);
            }
            __syncthreads();
            if (j < H1_) {
                const float* zb = (const float*)(sm + FB_ZBUF);
                float ig = sigm(zb[j]);
                float fg = sigm(zb[H1_ + j]);
                float gg = fmaxf(zb[2 * H1_ + j], 0.0f);
                float og = sigm(zb[3 * H1_ + j]);
                c1 = fg * c1 + ig * gg;
                float h = og * fmaxf(c1, 0.0f);
                h16 hh = (h16)h;
                *(h16*)(sm + FB_H1PK + 2 * j) = hh;
                *(h16*)(sm + FB_H1C + t * 208 + 2 * j) = hh;
            }
            __syncthreads();
        }
        stage_quads(W2, G2_, 13, H1_, sm + FB_W2Q, j);
        __syncthreads();
        {
            const float bj = b2[j];
            const uint4* WQ = (const uint4*)(sm + FB_W2Q);
            for (int t = 0; t < FBTC; ++t) {
                const uint4* HC = (const uint4*)(sm + FB_H1C + t * 208);
                float a0 = bj, a1 = 0.f, a2 = 0.f, a3 = 0.f;
                #pragma unroll
                for (int q = 0; q < 13; ++q) {
                    uint4 wq = WQ[q * G2_ + j]; uint4 hq = HC[q];
                    a0 = fd2(wq.x, hq.x, a0); a1 = fd2(wq.y, hq.y, a1);
                    a2 = fd2(wq.z, hq.z, a2); a3 = fd2(wq.w, hq.w, a3);
                }
                *(h16*)(sm + FB_XP2 + 2 * (t * G2_ + j)) = (h16)((a0 + a1) + (a2 + a3));
            }
        }
        __syncthreads();
        stage_quads(U2, G2_, 15, 120, sm + FB_U2Q, j);
        __syncthreads();
        for (int t = 0; t < FBTC; ++t) {
            {
                const uint4* WQ = (const uint4*)(sm + FB_U2Q);
                const uint4* HP = (const uint4*)(sm + FB_H2PK);
                float a0 = (float)*(const h16*)(sm + FB_XP2 + 2 * (t * G2_ + j));
                float a1 = 0.f, a2 = 0.f, a3 = 0.f;
                #pragma unroll
                for (int q = 0; q < 15; ++q) {
                    uint4 wq = WQ[q * G2_ + j]; uint4 hq = HP[q];
                    a0 = fd2(wq.x, hq.x, a0); a1 = fd2(wq.y, hq.y, a1);
                    a2 = fd2(wq.z, hq.z, a2); a3 = fd2(wq.w, hq.w, a3);
                }
                uint4 hp15 = ((const uint4*)(sm + FB_H2PK))[15];
                a0 = fd2(u2r0, hp15.x, a0); a1 = fd2(u2r1, hp15.y, a1);
                a2 = fd2(u2r2, hp15.z, a2); a3 = fd2(u2r3, hp15.w, a3);
                *(float*)(sm + FB_ZBUF + 4 * j) = (a0 + a1) + (a2 + a3);
            }
            __syncthreads();
            if (j < H2_) {
                const float* zb = (const float*)(sm + FB_ZBUF);
                float ig = sigm(zb[j]);
                float fg = sigm(zb[H2_ + j]);
                float gg = fmaxf(zb[2 * H2_ + j], 0.0f);
                float og = sigm(zb[3 * H2_ + j]);
                c2 = fg * c2 + ig * gg;
                float h = og * fmaxf(c2, 0.0f);
                *(h16*)(sm + FB_H2PK + 2 * j) = (h16)h;
                *(float*)(sm + FB_H2F + 4 * j) = h;
            }
            __syncthreads();
        }
    }
    if (j < OUT_) {
        const float* h2 = (const float*)(sm + FB_H2F);
        float acc = bd[j];
        #pragma unroll
        for (int k = 0; k < H2_; ++k) acc += h2[k] * Wd[k * OUT_ + j];
        *(float*)(sm + FB_ZBUF + 4 * j) = acc;
    }
    __syncthreads();
    if (j < OUT_) {
        const float* zb = (const float*)(sm + FB_ZBUF);
        float m = -1e30f;
        for (int k = 0; k < OUT_; ++k) m = fmaxf(m, zb[k]);
        float s = 0.0f;
        for (int k = 0; k < OUT_; ++k) s += expf(zb[k] - m);
        out[b * OUT_ + j] = expf(zb[j] - m) / s;
    }
}

// ================= launcher =================
extern "C" void kernel_launch(void* const* d_in, const int* in_sizes, int n_in,
                              void* d_out, int out_size, void* d_ws, size_t ws_size,
                              hipStream_t stream) {
    const float* x  = (const float*)d_in[0];
    const float* W1 = (const float*)d_in[1];
    const float* U1 = (const float*)d_in[2];
    const float* b1 = (const float*)d_in[3];
    const float* W2 = (const float*)d_in[4];
    const float* U2 = (const float*)d_in[5];
    const float* b2 = (const float*)d_in[6];
    const float* Wd = (const float*)d_in[7];
    const float* bd = (const float*)d_in[8];
    float* out = (float*)d_out;

    if (ws_size >= WS_A) {
        // ---- TIER A: lead-2 pipeline, dense1 AND dense2 as riders ----
        char* ws = (char*)d_ws;
        h16* xp1[2] = { (h16*)(ws + A_XP1A), (h16*)(ws + A_XP1B) };
        h16* xp2[2] = { (h16*)(ws + A_XP2A), (h16*)(ws + A_XP2B) };
        h16* h1g[2] = { (h16*)(ws + A_H1GA), (h16*)(ws + A_H1GB) };
        float* c1  = (float*)(ws + A_C1);
        float* c2  = (float*)(ws + A_C2);
        h16*   hs1 = (h16*)(ws + A_H1S);
        h16*   hs2 = (h16*)(ws + A_H2S);
        h16*   u1f = (h16*)(ws + A_U1F);
        h16*   u2f = (h16*)(ws + A_U2F);

        k_prepack<<<16, 512, 0, stream>>>(U1, U2, u1f, u2f);
        k_dense<0, 4><<<256, 512, 0, stream>>>(x, (const h16*)nullptr, W1, b1, H1_, 0, xp1[0]);
        // P-1: rec1(0) -> h1g[0]; rider dense1(1) -> xp1[1]
        k_mega<<<544, 512, 0, stream>>>(
            0, u2f, (const h16*)nullptr, c2, hs2, 0,
            1, u1f, xp1[0], h1g[0], c1, hs1, 0,
            0, (const h16*)nullptr, W2, b2, (h16*)nullptr,
            1, x, W1, b1, 1, xp1[1]);
        // P0: rec1(1) -> h1g[1]; riders dense2(0): h1g[0]->xp2[0], dense1(2)->xp1[0]
        k_mega<<<544, 512, 0, stream>>>(
            0, u2f, (const h16*)nullptr, c2, hs2, 0,
            1, u1f, xp1[1], h1g[1], c1, hs1, 1,
            1, h1g[0], W2, b2, xp2[0],
            1, x, W1, b1, 2, xp1[0]);
        for (int ch = 0; ch < NCH; ++ch) {
            const int r1on = (ch + 2 < NCH);
            const int d2on = (ch + 1 < NCH);
            const int d1on = (ch + 3 < NCH);
            k_mega<<<544, 512, 0, stream>>>(
                1, u2f, xp2[ch & 1], c2, hs2, ch,
                r1on, u1f, xp1[(ch + 2) & 1], h1g[(ch + 2) & 1], c1, hs1, ch + 2,
                d2on, h1g[(ch + 1) & 1], W2, b2, xp2[(ch + 1) & 1],
                d1on, x, W1, b1, ch + 3, xp1[(ch + 3) & 1]);
        }
        k_head<<<256, 64, 0, stream>>>(hs2, Wd, bd, out);
    } else if (ws_size >= WS_B) {
        // ---- TIER B: R17-proven lead-1 schedule ----
        char* ws = (char*)d_ws;
        h16* xp1[2] = { (h16*)(ws + B_XP1A), (h16*)(ws + B_XP1B) };
        h16*   xp2 = (h16*)(ws + B_XP2);
        h16*   h1g = (h16*)(ws + B_H1G);
        float* c1  = (float*)(ws + B_C1);
        float* c2  = (float*)(ws + B_C2);
        h16*   hs1 = (h16*)(ws + B_H1S);
        h16*   hs2 = (h16*)(ws + B_H2S);
        h16*   u1f = (h16*)(ws + B_U1F);
        h16*   u2f = (h16*)(ws + B_U2F);

        k_prepack<<<16, 512, 0, stream>>>(U1, U2, u1f, u2f);
        k_dense<0, 4><<<256, 512, 0, stream>>>(x, (const h16*)nullptr, W1, b1, H1_, 0, xp1[0]);
        // rec1(0) + dense1(1) rider
        k_mega<<<544, 512, 0, stream>>>(
            0, u2f, (const h16*)nullptr, c2, hs2, 0,
            1, u1f, xp1[0], h1g, c1, hs1, 0,
            0, (const h16*)nullptr, W2, b2, (h16*)nullptr,
            1, x, W1, b1, 1, xp1[1]);
        for (int ch = 0; ch < NCH; ++ch) {
            // dense2(ch) standalone (consumes h1g(ch))
            k_mega<<<288, 512, 0, stream>>>(
                0, u2f, (const h16*)nullptr, c2, hs2, 0,
                0, u1f, (const h16*)nullptr, (h16*)nullptr, c1, hs1, 0,
                1, h1g, W2, b2, xp2,
                0, x, W1, b1, 0, (h16*)nullptr);
            if (ch + 1 < NCH) {
                const int d1on = (ch + 2 < NCH);
                k_mega<<<544, 512, 0, stream>>>(
                    1, u2f, xp2, c2, hs2, ch,
                    1, u1f, xp1[(ch + 1) & 1], h1g, c1, hs1, ch + 1,
                    0, (const h16*)nullptr, W2, b2, (h16*)nullptr,
                    d1on, x, W1, b1, ch + 2, xp1[ch & 1]);
            } else {
                k_mega<<<16, 512, 0, stream>>>(
                    1, u2f, xp2, c2, hs2, ch,
                    0, u1f, (const h16*)nullptr, (h16*)nullptr, c1, hs1, 0,
                    0, (const h16*)nullptr, W2, b2, (h16*)nullptr,
                    0, x, W1, b1, 0, (h16*)nullptr);
            }
        }
        k_head<<<256, 64, 0, stream>>>(hs2, Wd, bd, out);
    } else {
        lstm_fallback<<<B_, 512, 0, stream>>>(x, W1, U1, b1, W2, U2, b2, Wd, bd, out);
    }
}